// Round 4
// baseline (1078.561 us; speedup 1.0000x reference)
//
#include <hip/hip_runtime.h>
#include <math.h>

#define TILE 64
#define KC 16

typedef __attribute__((ext_vector_type(8))) short short8;
typedef __attribute__((ext_vector_type(4))) float float4v;
typedef const __attribute__((address_space(1))) void* gptr_t;
typedef __attribute__((address_space(3))) void* lptr_t;

// ---------------- workspace layout (bytes) ----------------
#define OFF_PT    0ull          // 8192*512*4 = 16777216
#define OFF_YMAX  16777216ull   // 8388608
#define OFF_YMIN  25165824ull   // 8388608
#define OFF_YF    0ull          // alias: 8192*1024*4 = 33554432 (final gemm out; PT/ymax dead then)
#define OFF_IDX   67108864ull   // 655360
#define OFF_H     67764224ull   // 8388608
#define OFF_FUSB  76152832ull   // 8192*512*2 = 8388608 (bf16 fused)
#define OFF_WFB   84541440ull   // 1024*512*2 = 1048576 (bf16 Wf)
#define OFF_XX    85590016ull   // 8192 f64 = 65536
#define OFF_WCAT  85655552ull   // 262144
#define OFF_STATS 85917696ull   // 24576
#define OFF_COEF  85942272ull   // 12288

__device__ __forceinline__ unsigned short f2bf(float f) {
  unsigned int u = __float_as_uint(f);
  unsigned int r = (u + 0x7fffu + ((u >> 16) & 1u)) >> 16;
  return (unsigned short)r;
}

// ---------------- fp32 tiled GEMM core: C(M,N) = A(M,K) * Bw(N,K)^T ----------------
__device__ __forceinline__ void gemm_tile_loop(
    const float* __restrict__ A, const float* __restrict__ Bw,
    int K, int lda, int ldb, int rowBase, int colBase,
    float acc[4][4], float* As, float* Bs)
{
  const int tid = threadIdx.x;
  const int tx = tid & 15, ty = tid >> 4;
  for (int k0 = 0; k0 < K; k0 += KC) {
    for (int l = 0; l < 4; ++l) {
      int flat = tid * 4 + l;           // 0..1023
      int kk = flat & (KC - 1);
      int row = flat >> 4;
      int gk = k0 + kk;
      float av = 0.f, bv = 0.f;
      if (gk < K) {
        av = A[(size_t)(rowBase + row) * lda + gk];
        bv = Bw[(size_t)(colBase + row) * ldb + gk];
      }
      As[kk * TILE + row] = av;
      Bs[kk * TILE + row] = bv;
    }
    __syncthreads();
#pragma unroll
    for (int kk = 0; kk < KC; ++kk) {
      float a0[4], b0[4];
#pragma unroll
      for (int i = 0; i < 4; ++i) a0[i] = As[kk * TILE + ty * 4 + i];
#pragma unroll
      for (int j = 0; j < 4; ++j) b0[j] = Bs[kk * TILE + tx * 4 + j];
#pragma unroll
      for (int i = 0; i < 4; ++i)
#pragma unroll
        for (int j = 0; j < 4; ++j)
          acc[i][j] = fmaf(a0[i], b0[j], acc[i][j]);
    }
    __syncthreads();
  }
}

// ---------------- K0: squared norms per point (f64) ----------------
__global__ __launch_bounds__(256) void xx_kernel(const float* __restrict__ H, int C,
                                                 double* __restrict__ xx) {
  int m = blockIdx.x * 256 + threadIdx.x;
  if (m < 8192) {
    double s = 0.0;
    for (int c = 0; c < C; ++c) { double h = (double)H[(size_t)m * C + c]; s = fma(h, h, s); }
    xx[m] = s;
  }
}

// ---------------- fused KNN: distances (f64, on the fly) + top-20 extraction ----------------
// One block = 8 query rows (4 waves x 2 rows). Streams the batch's 1024 points
// through LDS in 64-col tiles; never materializes the distance matrix.
template<int C>
__global__ __launch_bounds__(256) void knn_kernel(const float* __restrict__ H,
                                                  const double* __restrict__ xx,
                                                  int* __restrict__ idx) {
  constexpr int STRIDE = (C & 1) ? C : (C + 1);   // odd stride -> conflict-free per-lane reads
  extern __shared__ char smem[];
  double* xi  = (double*)smem;                    // [8][C] query features (f64)
  float*  xcol = (float*)(smem + 8 * C * 8);      // [64][STRIDE] candidate tile (f32)

  const int tid = threadIdx.x;
  const int lane = tid & 63;
  const int w = tid >> 6;
  const int b = blockIdx.x >> 7;                  // batch 0..7
  const int rbase = b * 1024 + (blockIdx.x & 127) * 8;
  const int colbase = b * 1024;

  // load 8 query rows into LDS as f64
  for (int i = tid; i < 8 * C; i += 256) {
    int r = i / C, c = i - r * C;
    xi[r * C + c] = (double)H[(size_t)(rbase + r) * C + c];
  }

  const int r0 = w * 2, r1 = w * 2 + 1;
  const double xxi0 = xx[rbase + r0];
  const double xxi1 = xx[rbase + r1];
  const double* xr0 = xi + r0 * C;
  const double* xr1 = xi + r1 * C;

  double v0[16], v1[16];

  for (int t = 0; t < 16; ++t) {
    __syncthreads();                               // also covers initial xi load
    // stage 64 candidate points into LDS (coalesced)
    if (C == 3) {
      if (tid < 192) {
        int jj = tid / 3, c = tid - jj * 3;
        xcol[jj * STRIDE + c] = H[(size_t)(colbase + t * 64 + jj) * 3 + c];
      }
    } else {
      for (int f = tid * 4; f < 64 * C; f += 1024) {
        int jj = f / C, c0 = f - (f / C) * C;
        float4v val = *(const float4v*)(H + (size_t)(colbase + t * 64 + jj) * C + c0);
        xcol[jj * STRIDE + c0 + 0] = val.x;
        xcol[jj * STRIDE + c0 + 1] = val.y;
        xcol[jj * STRIDE + c0 + 2] = val.z;
        xcol[jj * STRIDE + c0 + 3] = val.w;
      }
    }
    __syncthreads();
    double a0 = 0.0, a1 = 0.0;
    const float* xc = xcol + lane * STRIDE;
#pragma unroll 8
    for (int c = 0; c < C; ++c) {
      double xj = (double)xc[c];
      a0 = fma(xj, xr0[c], a0);
      a1 = fma(xj, xr1[c], a1);
    }
    double xxj = xx[colbase + t * 64 + lane];
    v0[t] = 2.0 * a0 - xxi0 - xxj;
    v1[t] = 2.0 * a1 - xxi1 - xxj;
  }

  // top-20 extraction per row (ties -> smaller index, as lax.top_k)
#pragma unroll
  for (int rr = 0; rr < 2; ++rr) {
    double* v = rr ? v1 : v0;
    int* out = idx + (size_t)(rbase + w * 2 + rr) * 20;
    for (int j = 0; j < 20; ++j) {
      double bv = v[0]; int bt = 0;
#pragma unroll
      for (int t = 1; t < 16; ++t) if (v[t] > bv) { bv = v[t]; bt = t; }
      int bcol = lane + 64 * bt;
#pragma unroll
      for (int off = 1; off < 64; off <<= 1) {
        double ov = __shfl_xor(bv, off, 64);
        int    oc = __shfl_xor(bcol, off, 64);
        if (ov > bv || (ov == bv && oc < bcol)) { bv = ov; bcol = oc; }
      }
      if (lane == (bcol & 63)) v[bcol >> 6] = -INFINITY;
      if (lane == 0) out[j] = bcol;
    }
  }
}

// ---------------- K3a: Wcat = [W1 ; W2-W1]  (W is (out, 2C) row-major) ----------------
__global__ __launch_bounds__(256) void wcat_kernel(const float* __restrict__ W,
                                                   float* __restrict__ Wcat, int outc, int C) {
  int i = blockIdx.x * 256 + threadIdx.x;
  if (i < outc * C) {
    int o = i / C, c = i % C;
    float w1 = W[(size_t)o * 2 * C + c];
    float w2 = W[(size_t)o * 2 * C + C + c];
    Wcat[(size_t)o * C + c] = w1;
    Wcat[(size_t)(outc + o) * C + c] = w2 - w1;
  }
}

// ---------------- K3b: PT(M, 2*out) = H(M,C) @ Wcat^T ----------------
__global__ __launch_bounds__(256) void pt_gemm(const float* __restrict__ A,
                                               const float* __restrict__ Bw,
                                               float* __restrict__ Out, int K, int Nn) {
  __shared__ float As[KC * TILE], Bs[KC * TILE];
  int rowBase = blockIdx.y * 64, colBase = blockIdx.x * 64;
  float acc[4][4] = {};
  gemm_tile_loop(A, Bw, K, K, K, rowBase, colBase, acc, As, Bs);
  int tx = threadIdx.x & 15, ty = threadIdx.x >> 4;
#pragma unroll
  for (int i = 0; i < 4; ++i)
#pragma unroll
    for (int j = 0; j < 4; ++j)
      Out[(size_t)(rowBase + ty * 4 + i) * Nn + colBase + tx * 4 + j] = acc[i][j];
}

// ---------------- K4: gather + max/min over k + channel stats ----------------
__global__ __launch_bounds__(256) void edge_reduce(const float* __restrict__ PT,
                                                   const int* __restrict__ idx,
                                                   float* __restrict__ ymax, float* __restrict__ ymin,
                                                   double* __restrict__ sum, double* __restrict__ sumsq,
                                                   int outc, int l2) {
  __shared__ int sidx[16 * 20];
  __shared__ float ssum[256], ssq[256];
  int tid = threadIdx.x;
  int base = blockIdx.x * 16;
  for (int i = tid; i < 320; i += 256) sidx[i] = idx[base * 20 + i];
  __syncthreads();
  int o = tid & (outc - 1);
  int rs = tid >> l2;
  int R = 256 >> l2;
  int twoc = 2 * outc;
  float ls = 0.f, lq = 0.f;
  for (int r = rs; r < 16; r += R) {
    int m = base + r;
    int boff = (m >> 10) << 10;
    float tv = PT[(size_t)m * twoc + outc + o];
    float vmax = -INFINITY, vmin = INFINITY;
#pragma unroll
    for (int k = 0; k < 20; ++k) {
      int nb = sidx[r * 20 + k];
      float p = PT[(size_t)(boff + nb) * twoc + o];
      float y = p + tv;
      vmax = fmaxf(vmax, y);
      vmin = fminf(vmin, y);
      ls += y;
      lq = fmaf(y, y, lq);
    }
    ymax[(size_t)m * outc + o] = vmax;
    ymin[(size_t)m * outc + o] = vmin;
  }
  ssum[tid] = ls; ssq[tid] = lq;
  __syncthreads();
  if (tid < outc) {
    float s = ssum[tid], q = ssq[tid];
    for (int rr = 1; rr < R; ++rr) { s += ssum[tid + rr * outc]; q += ssq[tid + rr * outc]; }
    atomicAdd(&sum[tid], (double)s);
    atomicAdd(&sumsq[tid], (double)q);
  }
}

// ---------------- K5: per-channel affine coefficients from stats (f64) ----------------
__global__ __launch_bounds__(256) void coef_kernel(const double* __restrict__ sum,
                                                   const double* __restrict__ sumsq,
                                                   const float* __restrict__ g,
                                                   const float* __restrict__ b,
                                                   float* __restrict__ cA, float* __restrict__ cC,
                                                   int outc, double count) {
  int o = blockIdx.x * 256 + threadIdx.x;
  if (o < outc) {
    double mean = sum[o] / count;
    double var = sumsq[o] / count - mean * mean;
    double a = (double)g[o] / sqrt(var + 1e-5);
    cA[o] = (float)a;
    cC[o] = (float)((double)b[o] - mean * a);
  }
}

// ---------------- K6: pick max/min per sign(a), affine + LeakyReLU, scatter to H & fused(bf16) ----------------
__global__ __launch_bounds__(256) void edge_epi(const float* __restrict__ ymax,
                                                const float* __restrict__ ymin,
                                                const float* __restrict__ cA, const float* __restrict__ cC,
                                                float* __restrict__ Hout, unsigned short* __restrict__ fusedb,
                                                int outc, int l2, int choff) {
  int i = blockIdx.x * 256 + threadIdx.x;    // over 8192*outc
  int m = i >> l2;
  int o = i & (outc - 1);
  float a = cA[o], c = cC[o];
  float v = (a >= 0.f) ? ymax[i] : ymin[i];
  float y = fmaf(a, v, c);
  y = (y > 0.f) ? y : 0.2f * y;
  Hout[i] = y;
  fusedb[(size_t)m * 512 + choff + o] = f2bf(y);
}

// ---------------- K6b: fp32 -> bf16 elementwise ----------------
__global__ __launch_bounds__(256) void cvt_bf16(const float* __restrict__ in,
                                                unsigned short* __restrict__ out, int n) {
  int i = blockIdx.x * 256 + threadIdx.x;
  if (i < n) out[i] = f2bf(in[i]);
}

// ---------------- K7: final GEMM (MFMA bf16): yf(8192,1024) = fusedb @ Wfb^T ----------------
__global__ __launch_bounds__(256) void final_gemm_mfma(const unsigned short* __restrict__ A,
                                                       const unsigned short* __restrict__ B,
                                                       float* __restrict__ C) {
  __shared__ unsigned short As[128 * 32];
  __shared__ unsigned short Bs[128 * 32];
  const int tid = threadIdx.x;
  const int lane = tid & 63;
  const int w = tid >> 6;             // wave 0..3
  const int wm = w >> 1, wn = w & 1;  // 2x2 wave grid, each wave 64x64
  const int rowBase = blockIdx.y * 128;
  const int colBase = blockIdx.x * 128;
  const int quad = lane >> 4;
  const int l15 = lane & 15;

  float4v acc[4][4] = {};

  for (int k0 = 0; k0 < 512; k0 += 32) {
#pragma unroll
    for (int q = 0; q < 2; ++q) {
      int ch = (w * 2 + q) * 64 + lane;          // 0..511, 16B chunks
      int r = ch >> 2, cp = ch & 3;
      const unsigned short* ga = A + (size_t)(rowBase + r) * 512 + k0 + cp * 8;
      const unsigned short* gb = B + (size_t)(colBase + r) * 512 + k0 + cp * 8;
      __builtin_amdgcn_global_load_lds((gptr_t)ga, (lptr_t)(As + (size_t)(w * 2 + q) * 512), 16, 0, 0);
      __builtin_amdgcn_global_load_lds((gptr_t)gb, (lptr_t)(Bs + (size_t)(w * 2 + q) * 512), 16, 0, 0);
    }
    __syncthreads();
    short8 af[4], bf[4];
#pragma unroll
    for (int mi = 0; mi < 4; ++mi)
      af[mi] = *(const short8*)(As + (wm * 64 + mi * 16 + l15) * 32 + quad * 8);
#pragma unroll
    for (int ni = 0; ni < 4; ++ni)
      bf[ni] = *(const short8*)(Bs + (wn * 64 + ni * 16 + l15) * 32 + quad * 8);
#pragma unroll
    for (int mi = 0; mi < 4; ++mi)
#pragma unroll
      for (int ni = 0; ni < 4; ++ni)
        acc[mi][ni] = __builtin_amdgcn_mfma_f32_16x16x32_bf16(af[mi], bf[ni], acc[mi][ni], 0, 0, 0);
    __syncthreads();
  }
#pragma unroll
  for (int mi = 0; mi < 4; ++mi)
#pragma unroll
    for (int ni = 0; ni < 4; ++ni)
#pragma unroll
      for (int r = 0; r < 4; ++r) {
        int gm = rowBase + wm * 64 + mi * 16 + quad * 4 + r;
        int gn = colBase + wn * 64 + ni * 16 + l15;
        C[(size_t)gm * 1024 + gn] = acc[mi][ni][r];
      }
}

// ---------------- K7b: per-column sums of yf (for final BN stats) ----------------
__global__ __launch_bounds__(256) void col_stats(const float* __restrict__ yf,
                                                 double* __restrict__ sum, double* __restrict__ sumsq) {
  int col = blockIdx.x * 256 + threadIdx.x;   // 0..1023
  int r0 = blockIdx.y * 128;
  float s = 0.f, q = 0.f;
  for (int r = 0; r < 128; ++r) {
    float v = yf[(size_t)(r0 + r) * 1024 + col];
    s += v;
    q = fmaf(v, v, q);
  }
  atomicAdd(&sum[col], (double)s);
  atomicAdd(&sumsq[col], (double)q);
}

// ---------------- K8: final normalize + LeakyReLU ----------------
__global__ __launch_bounds__(256) void final_epi(const float* __restrict__ yf,
                                                 const float* __restrict__ cA, const float* __restrict__ cC,
                                                 float* __restrict__ out) {
  int i = blockIdx.x * 256 + threadIdx.x;     // over 8192*1024
  int o = i & 1023;
  float y = fmaf(cA[o], yf[i], cC[o]);
  out[i] = (y > 0.f) ? y : 0.2f * y;
}

extern "C" void kernel_launch(void* const* d_in, const int* in_sizes, int n_in,
                              void* d_out, int out_size, void* d_ws, size_t ws_size,
                              hipStream_t stream) {
  const float* x = (const float*)d_in[0];
  const float* W[4]  = {(const float*)d_in[1], (const float*)d_in[4], (const float*)d_in[7], (const float*)d_in[10]};
  const float* g[4]  = {(const float*)d_in[2], (const float*)d_in[5], (const float*)d_in[8], (const float*)d_in[11]};
  const float* bb[4] = {(const float*)d_in[3], (const float*)d_in[6], (const float*)d_in[9], (const float*)d_in[12]};
  const float* Wf  = (const float*)d_in[13];
  const float* gf  = (const float*)d_in[14];
  const float* bfp = (const float*)d_in[15];
  float* out = (float*)d_out;

  char* ws = (char*)d_ws;
  float*  PT    = (float*)(ws + OFF_PT);
  float*  ymax  = (float*)(ws + OFF_YMAX);
  float*  ymin  = (float*)(ws + OFF_YMIN);
  float*  yf    = (float*)(ws + OFF_YF);
  int*    idxb  = (int*)(ws + OFF_IDX);
  float*  Hbuf  = (float*)(ws + OFF_H);
  unsigned short* fusedb = (unsigned short*)(ws + OFF_FUSB);
  unsigned short* wfb    = (unsigned short*)(ws + OFF_WFB);
  double* xxb   = (double*)(ws + OFF_XX);
  float*  wcat  = (float*)(ws + OFF_WCAT);
  double* stats = (double*)(ws + OFF_STATS);
  float*  coefb = (float*)(ws + OFF_COEF);

  hipMemsetAsync(stats, 0, 24576, stream);   // zero all stat accumulators (ws is poisoned)
  cvt_bf16<<<(524288 + 255) / 256, 256, 0, stream>>>(Wf, wfb, 524288);

  const int Cin[4]   = {3, 64, 64, 128};
  const int Cout[4]  = {64, 64, 128, 256};
  const int choff[4] = {0, 64, 128, 256};
  const float* Hin = x;
  size_t soff = 0, coff = 0;

  for (int i = 0; i < 4; ++i) {
    int C = Cin[i], oc = Cout[i];
    int l2 = (oc == 64) ? 6 : (oc == 128) ? 7 : 8;
    double* sum = stats + soff;  double* sumsq = sum + oc;  soff += 2 * (size_t)oc;
    float* cA = coefb + coff;    float* cC = cA + oc;       coff += 2 * (size_t)oc;

    xx_kernel<<<32, 256, 0, stream>>>(Hin, C, xxb);
    if (C == 3) {
      size_t smem = 8 * 3 * 8 + 64 * 3 * 4;
      knn_kernel<3><<<1024, 256, smem, stream>>>(Hin, xxb, idxb);
    } else if (C == 64) {
      size_t smem = 8 * 64 * 8 + 64 * 65 * 4;
      knn_kernel<64><<<1024, 256, smem, stream>>>(Hin, xxb, idxb);
    } else {
      size_t smem = 8 * 128 * 8 + 64 * 129 * 4;
      knn_kernel<128><<<1024, 256, smem, stream>>>(Hin, xxb, idxb);
    }
    wcat_kernel<<<(oc * C + 255) / 256, 256, 0, stream>>>(W[i], wcat, oc, C);
    pt_gemm<<<dim3(2 * oc / 64, 128), 256, 0, stream>>>(Hin, wcat, PT, C, 2 * oc);
    edge_reduce<<<512, 256, 0, stream>>>(PT, idxb, ymax, ymin, sum, sumsq, oc, l2);
    coef_kernel<<<1, 256, 0, stream>>>(sum, sumsq, g[i], bb[i], cA, cC, oc, 163840.0);
    edge_epi<<<(8192 * oc) / 256, 256, 0, stream>>>(ymax, ymin, cA, cC, Hbuf, fusedb, oc, l2, choff[i]);
    Hin = Hbuf;
  }

  double* sumF = stats + soff;  double* sumsqF = sumF + 1024;
  float* cAF = coefb + coff;    float* cCF = cAF + 1024;
  final_gemm_mfma<<<dim3(8, 64), 256, 0, stream>>>(fusedb, wfb, yf);
  col_stats<<<dim3(4, 64), 256, 0, stream>>>(yf, sumF, sumsqF);
  coef_kernel<<<4, 256, 0, stream>>>(sumF, sumsqF, gf, bfp, cAF, cCF, 1024, 8192.0);
  final_epi<<<8192 * 1024 / 256, 256, 0, stream>>>(yf, cAF, cCF, out);
}

// Round 5
// 870.046 us; speedup vs baseline: 1.2397x; 1.2397x over previous
//
#include <hip/hip_runtime.h>
#include <math.h>

#define TILE 64
#define KC 16

typedef __attribute__((ext_vector_type(8))) short short8;
typedef __attribute__((ext_vector_type(4))) float float4v;
typedef const __attribute__((address_space(1))) void* gptr_t;
typedef __attribute__((address_space(3))) void* lptr_t;

// ---------------- workspace layout (bytes) ----------------
// Df (32MB f32 dist) aliased with PT/ymax/ymin (dead until topk consumed Df)
// and YF (final gemm out, after last layer).
#define OFF_DF    0ull          // 8192*1024*4 = 33554432
#define OFF_PT    0ull          // alias: 8192*512*4 = 16777216
#define OFF_YMAX  16777216ull   // alias: 8388608
#define OFF_YMIN  25165824ull   // alias: 8388608
#define OFF_YF    0ull          // alias: 8192*1024*4 = 33554432
#define OFF_IDX   67108864ull   // 655360
#define OFF_H     67764224ull   // 8388608
#define OFF_FUSB  76152832ull   // 8192*512*2 = 8388608 (bf16 fused)
#define OFF_WFB   84541440ull   // 1024*512*2 = 1048576 (bf16 Wf)
#define OFF_XX    85590016ull   // 8192 f32 = 32768
#define OFF_WCAT  85655552ull   // 262144
#define OFF_STATS 85917696ull   // 24576
#define OFF_COEF  85942272ull   // 12288

__device__ __forceinline__ unsigned short f2bf(float f) {
  unsigned int u = __float_as_uint(f);
  unsigned int r = (u + 0x7fffu + ((u >> 16) & 1u)) >> 16;
  return (unsigned short)r;
}

// ---------------- fp32 tiled GEMM core: C(M,N) = A(M,K) * Bw(N,K)^T ----------------
__device__ __forceinline__ void gemm_tile_loop(
    const float* __restrict__ A, const float* __restrict__ Bw,
    int K, int lda, int ldb, int rowBase, int colBase,
    float acc[4][4], float* As, float* Bs)
{
  const int tid = threadIdx.x;
  const int tx = tid & 15, ty = tid >> 4;
  for (int k0 = 0; k0 < K; k0 += KC) {
    for (int l = 0; l < 4; ++l) {
      int flat = tid * 4 + l;           // 0..1023
      int kk = flat & (KC - 1);
      int row = flat >> 4;
      int gk = k0 + kk;
      float av = 0.f, bv = 0.f;
      if (gk < K) {
        av = A[(size_t)(rowBase + row) * lda + gk];
        bv = Bw[(size_t)(colBase + row) * ldb + gk];
      }
      As[kk * TILE + row] = av;
      Bs[kk * TILE + row] = bv;
    }
    __syncthreads();
#pragma unroll
    for (int kk = 0; kk < KC; ++kk) {
      float a0[4], b0[4];
#pragma unroll
      for (int i = 0; i < 4; ++i) a0[i] = As[kk * TILE + ty * 4 + i];
#pragma unroll
      for (int j = 0; j < 4; ++j) b0[j] = Bs[kk * TILE + tx * 4 + j];
#pragma unroll
      for (int i = 0; i < 4; ++i)
#pragma unroll
        for (int j = 0; j < 4; ++j)
          acc[i][j] = fmaf(a0[i], b0[j], acc[i][j]);
    }
    __syncthreads();
  }
}

// ---------------- K0: squared norms per point (f32, prefilter only) ----------------
__global__ __launch_bounds__(256) void xxf_kernel(const float* __restrict__ H, int C,
                                                  float* __restrict__ xx) {
  int m = blockIdx.x * 256 + threadIdx.x;
  if (m < 8192) {
    float s = 0.f;
    for (int c = 0; c < C; ++c) { float h = H[(size_t)m * C + c]; s = fmaf(h, h, s); }
    xx[m] = s;
  }
}

// ---------------- K1: fp32 neg squared distance matrix (prefilter) ----------------
__global__ __launch_bounds__(256) void distf_kernel(const float* __restrict__ H, int C,
                                                    const float* __restrict__ xx,
                                                    float* __restrict__ Df) {
  __shared__ float As[KC * TILE], Bs[KC * TILE];
  int bz = blockIdx.z;
  int rowBase = bz * 1024 + blockIdx.y * 64;
  int colBase = bz * 1024 + blockIdx.x * 64;
  float acc[4][4] = {};
  gemm_tile_loop(H, H, C, C, C, rowBase, colBase, acc, As, Bs);
  int tx = threadIdx.x & 15, ty = threadIdx.x >> 4;
#pragma unroll
  for (int i = 0; i < 4; ++i) {
    int grow = rowBase + ty * 4 + i;               // global row 0..8191
    float xi = xx[grow];
#pragma unroll
    for (int j = 0; j < 4; ++j) {
      int gj = blockIdx.x * 64 + tx * 4 + j;       // col within batch 0..1023
      float v = 2.0f * acc[i][j] - xi - xx[colBase + tx * 4 + j];
      Df[(size_t)grow * 1024 + gj] = v;
    }
  }
}

// ---------------- K2: fp32 top-32 prefilter + exact f64 re-rank to top-20 ----------------
// One wave per row. Packed u64 keys: (sortable f32 << 10) | (1023-col) gives
// value-desc, index-asc ordering with a single unsigned compare.
template<int C>
__global__ __launch_bounds__(256) void topk_rerank(const float* __restrict__ Df,
                                                   const float* __restrict__ H,
                                                   int* __restrict__ idx) {
  __shared__ int cand[4][32];
  const int lane = threadIdx.x & 63;
  const int w = threadIdx.x >> 6;
  const int row = blockIdx.x * 4 + w;              // 0..8191
  const int b = row >> 10;
  const float* drow = Df + (size_t)row * 1024;

  unsigned long long key[16];
#pragma unroll
  for (int t = 0; t < 16; ++t) {
    int col = lane + 64 * t;
    unsigned int u = __float_as_uint(drow[col]);
    unsigned int s = (u & 0x80000000u) ? ~u : (u | 0x80000000u);
    key[t] = ((unsigned long long)s << 10) | (unsigned int)(1023 - col);
  }
  for (int j = 0; j < 32; ++j) {
    unsigned long long bv = key[0];
#pragma unroll
    for (int t = 1; t < 16; ++t) if (key[t] > bv) bv = key[t];
#pragma unroll
    for (int off = 1; off < 64; off <<= 1) {
      unsigned long long ov = (unsigned long long)__shfl_xor((long long)bv, off, 64);
      if (ov > bv) bv = ov;
    }
    int col = 1023 - (int)(bv & 1023u);
    if ((col & 63) == lane) key[col >> 6] = 0ull;  // owner clears
    if (lane == 0) cand[w][j] = col;
  }
  __syncthreads();

  // exact f64 re-rank of the 32 candidates (direct form, no cancellation)
  double nd; int cj;
  if (lane < 32) {
    cj = cand[w][lane];
    const float* xi = H + (size_t)row * C;
    const float* xj = H + ((size_t)(b * 1024 + cj)) * C;
    double s = 0.0;
    if (C == 3) {
      for (int c = 0; c < 3; ++c) {
        double d = (double)xi[c] - (double)xj[c];
        s = fma(d, d, s);
      }
    } else {
      for (int c = 0; c < C; c += 4) {
        float4v a = *(const float4v*)(xi + c);
        float4v bb = *(const float4v*)(xj + c);
        double d0 = (double)a.x - (double)bb.x;
        double d1 = (double)a.y - (double)bb.y;
        double d2 = (double)a.z - (double)bb.z;
        double d3 = (double)a.w - (double)bb.w;
        s = fma(d0, d0, s); s = fma(d1, d1, s);
        s = fma(d2, d2, s); s = fma(d3, d3, s);
      }
    }
    nd = -s;
  } else {
    nd = -INFINITY; cj = 1 << 20;
  }
  int* outp = idx + (size_t)row * 20;
  for (int j = 0; j < 20; ++j) {
    double bv = nd; int bj = cj;
#pragma unroll
    for (int off = 1; off < 64; off <<= 1) {
      double ov = __shfl_xor(bv, off, 64);
      int    oj = __shfl_xor(bj, off, 64);
      if (ov > bv || (ov == bv && oj < bj)) { bv = ov; bj = oj; }
    }
    if (cj == bj) nd = -INFINITY;                  // winner clears
    if (lane == 0) outp[j] = bj;
  }
}

// ---------------- K3a: Wcat = [W1 ; W2-W1]  (W is (out, 2C) row-major) ----------------
__global__ __launch_bounds__(256) void wcat_kernel(const float* __restrict__ W,
                                                   float* __restrict__ Wcat, int outc, int C) {
  int i = blockIdx.x * 256 + threadIdx.x;
  if (i < outc * C) {
    int o = i / C, c = i % C;
    float w1 = W[(size_t)o * 2 * C + c];
    float w2 = W[(size_t)o * 2 * C + C + c];
    Wcat[(size_t)o * C + c] = w1;
    Wcat[(size_t)(outc + o) * C + c] = w2 - w1;
  }
}

// ---------------- K3b: PT(M, 2*out) = H(M,C) @ Wcat^T ----------------
__global__ __launch_bounds__(256) void pt_gemm(const float* __restrict__ A,
                                               const float* __restrict__ Bw,
                                               float* __restrict__ Out, int K, int Nn) {
  __shared__ float As[KC * TILE], Bs[KC * TILE];
  int rowBase = blockIdx.y * 64, colBase = blockIdx.x * 64;
  float acc[4][4] = {};
  gemm_tile_loop(A, Bw, K, K, K, rowBase, colBase, acc, As, Bs);
  int tx = threadIdx.x & 15, ty = threadIdx.x >> 4;
#pragma unroll
  for (int i = 0; i < 4; ++i)
#pragma unroll
    for (int j = 0; j < 4; ++j)
      Out[(size_t)(rowBase + ty * 4 + i) * Nn + colBase + tx * 4 + j] = acc[i][j];
}

// ---------------- K4: gather + max/min over k + channel stats ----------------
__global__ __launch_bounds__(256) void edge_reduce(const float* __restrict__ PT,
                                                   const int* __restrict__ idx,
                                                   float* __restrict__ ymax, float* __restrict__ ymin,
                                                   double* __restrict__ sum, double* __restrict__ sumsq,
                                                   int outc, int l2) {
  __shared__ int sidx[16 * 20];
  __shared__ float ssum[256], ssq[256];
  int tid = threadIdx.x;
  int base = blockIdx.x * 16;
  for (int i = tid; i < 320; i += 256) sidx[i] = idx[base * 20 + i];
  __syncthreads();
  int o = tid & (outc - 1);
  int rs = tid >> l2;
  int R = 256 >> l2;
  int twoc = 2 * outc;
  float ls = 0.f, lq = 0.f;
  for (int r = rs; r < 16; r += R) {
    int m = base + r;
    int boff = (m >> 10) << 10;
    float tv = PT[(size_t)m * twoc + outc + o];
    float vmax = -INFINITY, vmin = INFINITY;
#pragma unroll
    for (int k = 0; k < 20; ++k) {
      int nb = sidx[r * 20 + k];
      float p = PT[(size_t)(boff + nb) * twoc + o];
      float y = p + tv;
      vmax = fmaxf(vmax, y);
      vmin = fminf(vmin, y);
      ls += y;
      lq = fmaf(y, y, lq);
    }
    ymax[(size_t)m * outc + o] = vmax;
    ymin[(size_t)m * outc + o] = vmin;
  }
  ssum[tid] = ls; ssq[tid] = lq;
  __syncthreads();
  if (tid < outc) {
    float s = ssum[tid], q = ssq[tid];
    for (int rr = 1; rr < R; ++rr) { s += ssum[tid + rr * outc]; q += ssq[tid + rr * outc]; }
    atomicAdd(&sum[tid], (double)s);
    atomicAdd(&sumsq[tid], (double)q);
  }
}

// ---------------- K5: per-channel affine coefficients from stats (f64) ----------------
__global__ __launch_bounds__(256) void coef_kernel(const double* __restrict__ sum,
                                                   const double* __restrict__ sumsq,
                                                   const float* __restrict__ g,
                                                   const float* __restrict__ b,
                                                   float* __restrict__ cA, float* __restrict__ cC,
                                                   int outc, double count) {
  int o = blockIdx.x * 256 + threadIdx.x;
  if (o < outc) {
    double mean = sum[o] / count;
    double var = sumsq[o] / count - mean * mean;
    double a = (double)g[o] / sqrt(var + 1e-5);
    cA[o] = (float)a;
    cC[o] = (float)((double)b[o] - mean * a);
  }
}

// ---------------- K6: pick max/min per sign(a), affine + LeakyReLU, scatter to H & fused(bf16) ----------------
__global__ __launch_bounds__(256) void edge_epi(const float* __restrict__ ymax,
                                                const float* __restrict__ ymin,
                                                const float* __restrict__ cA, const float* __restrict__ cC,
                                                float* __restrict__ Hout, unsigned short* __restrict__ fusedb,
                                                int outc, int l2, int choff) {
  int i = blockIdx.x * 256 + threadIdx.x;    // over 8192*outc
  int m = i >> l2;
  int o = i & (outc - 1);
  float a = cA[o], c = cC[o];
  float v = (a >= 0.f) ? ymax[i] : ymin[i];
  float y = fmaf(a, v, c);
  y = (y > 0.f) ? y : 0.2f * y;
  Hout[i] = y;
  fusedb[(size_t)m * 512 + choff + o] = f2bf(y);
}

// ---------------- K6b: fp32 -> bf16 elementwise ----------------
__global__ __launch_bounds__(256) void cvt_bf16(const float* __restrict__ in,
                                                unsigned short* __restrict__ out, int n) {
  int i = blockIdx.x * 256 + threadIdx.x;
  if (i < n) out[i] = f2bf(in[i]);
}

// ---------------- K7: final GEMM (MFMA bf16): yf(8192,1024) = fusedb @ Wfb^T ----------------
__global__ __launch_bounds__(256) void final_gemm_mfma(const unsigned short* __restrict__ A,
                                                       const unsigned short* __restrict__ B,
                                                       float* __restrict__ C) {
  __shared__ unsigned short As[128 * 32];
  __shared__ unsigned short Bs[128 * 32];
  const int tid = threadIdx.x;
  const int lane = tid & 63;
  const int w = tid >> 6;             // wave 0..3
  const int wm = w >> 1, wn = w & 1;  // 2x2 wave grid, each wave 64x64
  const int rowBase = blockIdx.y * 128;
  const int colBase = blockIdx.x * 128;
  const int quad = lane >> 4;
  const int l15 = lane & 15;

  float4v acc[4][4] = {};

  for (int k0 = 0; k0 < 512; k0 += 32) {
#pragma unroll
    for (int q = 0; q < 2; ++q) {
      int ch = (w * 2 + q) * 64 + lane;          // 0..511, 16B chunks
      int r = ch >> 2, cp = ch & 3;
      const unsigned short* ga = A + (size_t)(rowBase + r) * 512 + k0 + cp * 8;
      const unsigned short* gb = B + (size_t)(colBase + r) * 512 + k0 + cp * 8;
      __builtin_amdgcn_global_load_lds((gptr_t)ga, (lptr_t)(As + (size_t)(w * 2 + q) * 512), 16, 0, 0);
      __builtin_amdgcn_global_load_lds((gptr_t)gb, (lptr_t)(Bs + (size_t)(w * 2 + q) * 512), 16, 0, 0);
    }
    __syncthreads();
    short8 af[4], bf[4];
#pragma unroll
    for (int mi = 0; mi < 4; ++mi)
      af[mi] = *(const short8*)(As + (wm * 64 + mi * 16 + l15) * 32 + quad * 8);
#pragma unroll
    for (int ni = 0; ni < 4; ++ni)
      bf[ni] = *(const short8*)(Bs + (wn * 64 + ni * 16 + l15) * 32 + quad * 8);
#pragma unroll
    for (int mi = 0; mi < 4; ++mi)
#pragma unroll
      for (int ni = 0; ni < 4; ++ni)
        acc[mi][ni] = __builtin_amdgcn_mfma_f32_16x16x32_bf16(af[mi], bf[ni], acc[mi][ni], 0, 0, 0);
    __syncthreads();
  }
#pragma unroll
  for (int mi = 0; mi < 4; ++mi)
#pragma unroll
    for (int ni = 0; ni < 4; ++ni)
#pragma unroll
      for (int r = 0; r < 4; ++r) {
        int gm = rowBase + wm * 64 + mi * 16 + quad * 4 + r;
        int gn = colBase + wn * 64 + ni * 16 + l15;
        C[(size_t)gm * 1024 + gn] = acc[mi][ni][r];
      }
}

// ---------------- K7b: per-column sums of yf (for final BN stats) ----------------
__global__ __launch_bounds__(256) void col_stats(const float* __restrict__ yf,
                                                 double* __restrict__ sum, double* __restrict__ sumsq) {
  int col = blockIdx.x * 256 + threadIdx.x;   // 0..1023
  int r0 = blockIdx.y * 128;
  float s = 0.f, q = 0.f;
  for (int r = 0; r < 128; ++r) {
    float v = yf[(size_t)(r0 + r) * 1024 + col];
    s += v;
    q = fmaf(v, v, q);
  }
  atomicAdd(&sum[col], (double)s);
  atomicAdd(&sumsq[col], (double)q);
}

// ---------------- K8: final normalize + LeakyReLU ----------------
__global__ __launch_bounds__(256) void final_epi(const float* __restrict__ yf,
                                                 const float* __restrict__ cA, const float* __restrict__ cC,
                                                 float* __restrict__ out) {
  int i = blockIdx.x * 256 + threadIdx.x;     // over 8192*1024
  int o = i & 1023;
  float y = fmaf(cA[o], yf[i], cC[o]);
  out[i] = (y > 0.f) ? y : 0.2f * y;
}

extern "C" void kernel_launch(void* const* d_in, const int* in_sizes, int n_in,
                              void* d_out, int out_size, void* d_ws, size_t ws_size,
                              hipStream_t stream) {
  const float* x = (const float*)d_in[0];
  const float* W[4]  = {(const float*)d_in[1], (const float*)d_in[4], (const float*)d_in[7], (const float*)d_in[10]};
  const float* g[4]  = {(const float*)d_in[2], (const float*)d_in[5], (const float*)d_in[8], (const float*)d_in[11]};
  const float* bb[4] = {(const float*)d_in[3], (const float*)d_in[6], (const float*)d_in[9], (const float*)d_in[12]};
  const float* Wf  = (const float*)d_in[13];
  const float* gf  = (const float*)d_in[14];
  const float* bfp = (const float*)d_in[15];
  float* out = (float*)d_out;

  char* ws = (char*)d_ws;
  float*  Df    = (float*)(ws + OFF_DF);
  float*  PT    = (float*)(ws + OFF_PT);
  float*  ymax  = (float*)(ws + OFF_YMAX);
  float*  ymin  = (float*)(ws + OFF_YMIN);
  float*  yf    = (float*)(ws + OFF_YF);
  int*    idxb  = (int*)(ws + OFF_IDX);
  float*  Hbuf  = (float*)(ws + OFF_H);
  unsigned short* fusedb = (unsigned short*)(ws + OFF_FUSB);
  unsigned short* wfb    = (unsigned short*)(ws + OFF_WFB);
  float*  xxb   = (float*)(ws + OFF_XX);
  float*  wcat  = (float*)(ws + OFF_WCAT);
  double* stats = (double*)(ws + OFF_STATS);
  float*  coefb = (float*)(ws + OFF_COEF);

  hipMemsetAsync(stats, 0, 24576, stream);   // zero all stat accumulators (ws is poisoned)
  cvt_bf16<<<(524288 + 255) / 256, 256, 0, stream>>>(Wf, wfb, 524288);

  const int Cin[4]   = {3, 64, 64, 128};
  const int Cout[4]  = {64, 64, 128, 256};
  const int choff[4] = {0, 64, 128, 256};
  const float* Hin = x;
  size_t soff = 0, coff = 0;

  for (int i = 0; i < 4; ++i) {
    int C = Cin[i], oc = Cout[i];
    int l2 = (oc == 64) ? 6 : (oc == 128) ? 7 : 8;
    double* sum = stats + soff;  double* sumsq = sum + oc;  soff += 2 * (size_t)oc;
    float* cA = coefb + coff;    float* cC = cA + oc;       coff += 2 * (size_t)oc;

    xxf_kernel<<<32, 256, 0, stream>>>(Hin, C, xxb);
    distf_kernel<<<dim3(16, 16, 8), 256, 0, stream>>>(Hin, C, xxb, Df);
    if (C == 3)       topk_rerank<3><<<2048, 256, 0, stream>>>(Df, Hin, idxb);
    else if (C == 64) topk_rerank<64><<<2048, 256, 0, stream>>>(Df, Hin, idxb);
    else              topk_rerank<128><<<2048, 256, 0, stream>>>(Df, Hin, idxb);
    wcat_kernel<<<(oc * C + 255) / 256, 256, 0, stream>>>(W[i], wcat, oc, C);
    pt_gemm<<<dim3(2 * oc / 64, 128), 256, 0, stream>>>(Hin, wcat, PT, C, 2 * oc);
    edge_reduce<<<512, 256, 0, stream>>>(PT, idxb, ymax, ymin, sum, sumsq, oc, l2);
    coef_kernel<<<1, 256, 0, stream>>>(sum, sumsq, g[i], bb[i], cA, cC, oc, 163840.0);
    edge_epi<<<(8192 * oc) / 256, 256, 0, stream>>>(ymax, ymin, cA, cC, Hbuf, fusedb, oc, l2, choff[i]);
    Hin = Hbuf;
  }

  double* sumF = stats + soff;  double* sumsqF = sumF + 1024;
  float* cAF = coefb + coff;    float* cCF = cAF + 1024;
  final_gemm_mfma<<<dim3(8, 64), 256, 0, stream>>>(fusedb, wfb, yf);
  col_stats<<<dim3(4, 64), 256, 0, stream>>>(yf, sumF, sumsqF);
  coef_kernel<<<4, 256, 0, stream>>>(sumF, sumsqF, gf, bfp, cAF, cCF, 1024, 8192.0);
  final_epi<<<8192 * 1024 / 256, 256, 0, stream>>>(yf, cAF, cCF, out);
}

// Round 6
// 637.842 us; speedup vs baseline: 1.6910x; 1.3640x over previous
//
#include <hip/hip_runtime.h>
#include <math.h>

#define TILE 64
#define KC 16

typedef __attribute__((ext_vector_type(8))) short short8;
typedef __attribute__((ext_vector_type(4))) float float4v;
typedef const __attribute__((address_space(1))) void* gptr_t;
typedef __attribute__((address_space(3))) void* lptr_t;

// ---------------- workspace layout (bytes) ----------------
#define OFF_DF    0ull          // 8192*1024*4 = 33554432
#define OFF_PT    0ull          // alias: 8192*512*4 = 16777216
#define OFF_YMAX  16777216ull   // alias: 8388608
#define OFF_YMIN  25165824ull   // alias: 8388608
#define OFF_YF    0ull          // alias: 8192*1024*4 = 33554432
#define OFF_IDX   67108864ull   // 655360
#define OFF_H     67764224ull   // 8388608
#define OFF_FUSB  76152832ull   // 8192*512*2 = 8388608 (bf16 fused)
#define OFF_WFB   84541440ull   // 1024*512*2 = 1048576 (bf16 Wf)
#define OFF_XX    85590016ull   // 8192 f32 = 32768
#define OFF_WCAT  85655552ull   // 262144
#define OFF_STATS 85917696ull   // 24576
#define OFF_COEF  85942272ull   // 12288

__device__ __forceinline__ unsigned short f2bf(float f) {
  unsigned int u = __float_as_uint(f);
  unsigned int r = (u + 0x7fffu + ((u >> 16) & 1u)) >> 16;
  return (unsigned short)r;
}

// ---------------- fp32 tiled GEMM core: C(M,N) = A(M,K) * Bw(N,K)^T ----------------
__device__ __forceinline__ void gemm_tile_loop(
    const float* __restrict__ A, const float* __restrict__ Bw,
    int K, int lda, int ldb, int rowBase, int colBase,
    float acc[4][4], float* As, float* Bs)
{
  const int tid = threadIdx.x;
  const int tx = tid & 15, ty = tid >> 4;
  for (int k0 = 0; k0 < K; k0 += KC) {
    for (int l = 0; l < 4; ++l) {
      int flat = tid * 4 + l;           // 0..1023
      int kk = flat & (KC - 1);
      int row = flat >> 4;
      int gk = k0 + kk;
      float av = 0.f, bv = 0.f;
      if (gk < K) {
        av = A[(size_t)(rowBase + row) * lda + gk];
        bv = Bw[(size_t)(colBase + row) * ldb + gk];
      }
      As[kk * TILE + row] = av;
      Bs[kk * TILE + row] = bv;
    }
    __syncthreads();
#pragma unroll
    for (int kk = 0; kk < KC; ++kk) {
      float a0[4], b0[4];
#pragma unroll
      for (int i = 0; i < 4; ++i) a0[i] = As[kk * TILE + ty * 4 + i];
#pragma unroll
      for (int j = 0; j < 4; ++j) b0[j] = Bs[kk * TILE + tx * 4 + j];
#pragma unroll
      for (int i = 0; i < 4; ++i)
#pragma unroll
        for (int j = 0; j < 4; ++j)
          acc[i][j] = fmaf(a0[i], b0[j], acc[i][j]);
    }
    __syncthreads();
  }
}

// ---------------- K0: squared norms per point (f32, prefilter only) ----------------
__global__ __launch_bounds__(256) void xxf_kernel(const float* __restrict__ H, int C,
                                                  float* __restrict__ xx) {
  int m = blockIdx.x * 256 + threadIdx.x;
  if (m < 8192) {
    float s = 0.f;
    for (int c = 0; c < C; ++c) { float h = H[(size_t)m * C + c]; s = fmaf(h, h, s); }
    xx[m] = s;
  }
}

// ---------------- K1: fp32 neg squared distance matrix (prefilter) ----------------
__global__ __launch_bounds__(256) void distf_kernel(const float* __restrict__ H, int C,
                                                    const float* __restrict__ xx,
                                                    float* __restrict__ Df) {
  __shared__ float As[KC * TILE], Bs[KC * TILE];
  int bz = blockIdx.z;
  int rowBase = bz * 1024 + blockIdx.y * 64;
  int colBase = bz * 1024 + blockIdx.x * 64;
  float acc[4][4] = {};
  gemm_tile_loop(H, H, C, C, C, rowBase, colBase, acc, As, Bs);
  int tx = threadIdx.x & 15, ty = threadIdx.x >> 4;
#pragma unroll
  for (int i = 0; i < 4; ++i) {
    int grow = rowBase + ty * 4 + i;               // global row 0..8191
    float xi = xx[grow];
#pragma unroll
    for (int j = 0; j < 4; ++j) {
      int gj = blockIdx.x * 64 + tx * 4 + j;       // col within batch 0..1023
      float v = 2.0f * acc[i][j] - xi - xx[colBase + tx * 4 + j];
      Df[(size_t)grow * 1024 + gj] = v;
    }
  }
}

// ---------------- K2: threshold-bisection top-[32..64] superset + exact f64 rank -> top-20 set ----
// One wave per row; 4 rows per block. No __syncthreads (waves diverge); all LDS
// traffic is wave-private (DS ops are in-order within a wave).
template<int C>
__global__ __launch_bounds__(256) void topk_rerank(const float* __restrict__ Df,
                                                   const float* __restrict__ H,
                                                   int* __restrict__ idx) {
  __shared__ int    candLds[4][64];
  __shared__ double ndLds[4][64];
  __shared__ int    colLds[4][64];
  const int lane = threadIdx.x & 63;
  const int w = threadIdx.x >> 6;
  const int row = blockIdx.x * 4 + w;              // 0..8191
  const int b = row >> 10;
  const float* drow = Df + (size_t)row * 1024;

  // sortable u32 keys (value order only; cols tracked by position)
  unsigned s[16];
#pragma unroll
  for (int t = 0; t < 16; ++t) {
    unsigned u = __float_as_uint(drow[lane + 64 * t]);
    s[t] = (u & 0x80000000u) ? ~u : (u | 0x80000000u);
  }

  // bisect threshold p so that selected = {s > p} has 32..64 members.
  // Invariant: stored p always has count >= 32. Early-exit when count <= 64.
  unsigned p = 0;
  for (int bit = 31; bit >= 0; --bit) {
    unsigned cand = p | (1u << bit);
    int c = 0;
#pragma unroll
    for (int t = 0; t < 16; ++t) c += (s[t] > cand) ? 1 : 0;
#pragma unroll
    for (int off = 1; off < 64; off <<= 1) c += __shfl_xor(c, off, 64);
    if (c >= 32) {
      p = cand;
      if (c <= 64) break;
    }
  }

  // compact selected columns into per-wave LDS (clamped to 64; >64 requires a
  // >33-way exact-f32 tie at the boundary -- measure-zero for this data)
  int k = 0;
#pragma unroll
  for (int t = 0; t < 16; ++t) k += (s[t] > p) ? 1 : 0;
  int incl = k;
#pragma unroll
  for (int off = 1; off < 64; off <<= 1) {
    int v = __shfl_up(incl, off, 64);
    if (lane >= off) incl += v;
  }
  int slot = incl - k;
#pragma unroll
  for (int t = 0; t < 16; ++t) {
    if (s[t] > p) {
      if (slot < 64) candLds[w][slot] = lane + 64 * t;
      ++slot;
    }
  }
  int nsel = __shfl(incl, 63, 64);
  if (nsel > 64) nsel = 64;

  // exact f64 re-rank (direct form, no cancellation), one candidate per lane
  double nd; int col;
  if (lane < nsel) {
    col = candLds[w][lane];
    const float* xi = H + (size_t)row * C;
    const float* xj = H + (size_t)(b * 1024 + col) * C;
    double ssum = 0.0;
    if (C == 3) {
#pragma unroll
      for (int c = 0; c < 3; ++c) {
        double d = (double)xi[c] - (double)xj[c];
        ssum = fma(d, d, ssum);
      }
    } else {
      for (int c = 0; c < C; c += 4) {
        float4v a = *(const float4v*)(xi + c);
        float4v bb = *(const float4v*)(xj + c);
        double d0 = (double)a.x - (double)bb.x;
        double d1 = (double)a.y - (double)bb.y;
        double d2 = (double)a.z - (double)bb.z;
        double d3 = (double)a.w - (double)bb.w;
        ssum = fma(d0, d0, ssum); ssum = fma(d1, d1, ssum);
        ssum = fma(d2, d2, ssum); ssum = fma(d3, d3, ssum);
      }
    }
    nd = -ssum;
  } else {
    nd = -INFINITY; col = 100000 + lane;           // unique, loses all compares
  }
  ndLds[w][lane] = nd;
  colLds[w][lane] = col;

  // rank by counting beats (value desc, col asc) -- LDS broadcast reads
  int rank = 0;
#pragma unroll 4
  for (int j = 0; j < 64; ++j) {
    double vj = ndLds[w][j];
    int cj = colLds[w][j];
    rank += (vj > nd || (vj == nd && cj < col)) ? 1 : 0;
  }
  if (rank < 20) idx[(size_t)row * 20 + rank] = col;
}

// ---------------- K3a: Wcat = [W1 ; W2-W1]  (W is (out, 2C) row-major) ----------------
__global__ __launch_bounds__(256) void wcat_kernel(const float* __restrict__ W,
                                                   float* __restrict__ Wcat, int outc, int C) {
  int i = blockIdx.x * 256 + threadIdx.x;
  if (i < outc * C) {
    int o = i / C, c = i % C;
    float w1 = W[(size_t)o * 2 * C + c];
    float w2 = W[(size_t)o * 2 * C + C + c];
    Wcat[(size_t)o * C + c] = w1;
    Wcat[(size_t)(outc + o) * C + c] = w2 - w1;
  }
}

// ---------------- K3b: PT(M, 2*out) = H(M,C) @ Wcat^T ----------------
__global__ __launch_bounds__(256) void pt_gemm(const float* __restrict__ A,
                                               const float* __restrict__ Bw,
                                               float* __restrict__ Out, int K, int Nn) {
  __shared__ float As[KC * TILE], Bs[KC * TILE];
  int rowBase = blockIdx.y * 64, colBase = blockIdx.x * 64;
  float acc[4][4] = {};
  gemm_tile_loop(A, Bw, K, K, K, rowBase, colBase, acc, As, Bs);
  int tx = threadIdx.x & 15, ty = threadIdx.x >> 4;
#pragma unroll
  for (int i = 0; i < 4; ++i)
#pragma unroll
    for (int j = 0; j < 4; ++j)
      Out[(size_t)(rowBase + ty * 4 + i) * Nn + colBase + tx * 4 + j] = acc[i][j];
}

// ---------------- K4: gather + max/min over k + channel stats ----------------
__global__ __launch_bounds__(256) void edge_reduce(const float* __restrict__ PT,
                                                   const int* __restrict__ idx,
                                                   float* __restrict__ ymax, float* __restrict__ ymin,
                                                   double* __restrict__ sum, double* __restrict__ sumsq,
                                                   int outc, int l2) {
  __shared__ int sidx[16 * 20];
  __shared__ float ssum[256], ssq[256];
  int tid = threadIdx.x;
  int base = blockIdx.x * 16;
  for (int i = tid; i < 320; i += 256) sidx[i] = idx[base * 20 + i];
  __syncthreads();
  int o = tid & (outc - 1);
  int rs = tid >> l2;
  int R = 256 >> l2;
  int twoc = 2 * outc;
  float ls = 0.f, lq = 0.f;
  for (int r = rs; r < 16; r += R) {
    int m = base + r;
    int boff = (m >> 10) << 10;
    float tv = PT[(size_t)m * twoc + outc + o];
    float vmax = -INFINITY, vmin = INFINITY;
#pragma unroll
    for (int k = 0; k < 20; ++k) {
      int nb = sidx[r * 20 + k];
      float p = PT[(size_t)(boff + nb) * twoc + o];
      float y = p + tv;
      vmax = fmaxf(vmax, y);
      vmin = fminf(vmin, y);
      ls += y;
      lq = fmaf(y, y, lq);
    }
    ymax[(size_t)m * outc + o] = vmax;
    ymin[(size_t)m * outc + o] = vmin;
  }
  ssum[tid] = ls; ssq[tid] = lq;
  __syncthreads();
  if (tid < outc) {
    float s = ssum[tid], q = ssq[tid];
    for (int rr = 1; rr < R; ++rr) { s += ssum[tid + rr * outc]; q += ssq[tid + rr * outc]; }
    atomicAdd(&sum[tid], (double)s);
    atomicAdd(&sumsq[tid], (double)q);
  }
}

// ---------------- K5: per-channel affine coefficients from stats (f64) ----------------
__global__ __launch_bounds__(256) void coef_kernel(const double* __restrict__ sum,
                                                   const double* __restrict__ sumsq,
                                                   const float* __restrict__ g,
                                                   const float* __restrict__ b,
                                                   float* __restrict__ cA, float* __restrict__ cC,
                                                   int outc, double count) {
  int o = blockIdx.x * 256 + threadIdx.x;
  if (o < outc) {
    double mean = sum[o] / count;
    double var = sumsq[o] / count - mean * mean;
    double a = (double)g[o] / sqrt(var + 1e-5);
    cA[o] = (float)a;
    cC[o] = (float)((double)b[o] - mean * a);
  }
}

// ---------------- K6: pick max/min per sign(a), affine + LeakyReLU, scatter to H & fused(bf16) ----------------
__global__ __launch_bounds__(256) void edge_epi(const float* __restrict__ ymax,
                                                const float* __restrict__ ymin,
                                                const float* __restrict__ cA, const float* __restrict__ cC,
                                                float* __restrict__ Hout, unsigned short* __restrict__ fusedb,
                                                int outc, int l2, int choff) {
  int i = blockIdx.x * 256 + threadIdx.x;    // over 8192*outc
  int m = i >> l2;
  int o = i & (outc - 1);
  float a = cA[o], c = cC[o];
  float v = (a >= 0.f) ? ymax[i] : ymin[i];
  float y = fmaf(a, v, c);
  y = (y > 0.f) ? y : 0.2f * y;
  Hout[i] = y;
  fusedb[(size_t)m * 512 + choff + o] = f2bf(y);
}

// ---------------- K6b: fp32 -> bf16 elementwise ----------------
__global__ __launch_bounds__(256) void cvt_bf16(const float* __restrict__ in,
                                                unsigned short* __restrict__ out, int n) {
  int i = blockIdx.x * 256 + threadIdx.x;
  if (i < n) out[i] = f2bf(in[i]);
}

// ---------------- K7: final GEMM (MFMA bf16): yf(8192,1024) = fusedb @ Wfb^T ----------------
__global__ __launch_bounds__(256) void final_gemm_mfma(const unsigned short* __restrict__ A,
                                                       const unsigned short* __restrict__ B,
                                                       float* __restrict__ C) {
  __shared__ unsigned short As[128 * 32];
  __shared__ unsigned short Bs[128 * 32];
  const int tid = threadIdx.x;
  const int lane = tid & 63;
  const int w = tid >> 6;             // wave 0..3
  const int wm = w >> 1, wn = w & 1;  // 2x2 wave grid, each wave 64x64
  const int rowBase = blockIdx.y * 128;
  const int colBase = blockIdx.x * 128;
  const int quad = lane >> 4;
  const int l15 = lane & 15;

  float4v acc[4][4] = {};

  for (int k0 = 0; k0 < 512; k0 += 32) {
#pragma unroll
    for (int q = 0; q < 2; ++q) {
      int ch = (w * 2 + q) * 64 + lane;          // 0..511, 16B chunks
      int r = ch >> 2, cp = ch & 3;
      const unsigned short* ga = A + (size_t)(rowBase + r) * 512 + k0 + cp * 8;
      const unsigned short* gb = B + (size_t)(colBase + r) * 512 + k0 + cp * 8;
      __builtin_amdgcn_global_load_lds((gptr_t)ga, (lptr_t)(As + (size_t)(w * 2 + q) * 512), 16, 0, 0);
      __builtin_amdgcn_global_load_lds((gptr_t)gb, (lptr_t)(Bs + (size_t)(w * 2 + q) * 512), 16, 0, 0);
    }
    __syncthreads();
    short8 af[4], bf[4];
#pragma unroll
    for (int mi = 0; mi < 4; ++mi)
      af[mi] = *(const short8*)(As + (wm * 64 + mi * 16 + l15) * 32 + quad * 8);
#pragma unroll
    for (int ni = 0; ni < 4; ++ni)
      bf[ni] = *(const short8*)(Bs + (wn * 64 + ni * 16 + l15) * 32 + quad * 8);
#pragma unroll
    for (int mi = 0; mi < 4; ++mi)
#pragma unroll
      for (int ni = 0; ni < 4; ++ni)
        acc[mi][ni] = __builtin_amdgcn_mfma_f32_16x16x32_bf16(af[mi], bf[ni], acc[mi][ni], 0, 0, 0);
    __syncthreads();
  }
#pragma unroll
  for (int mi = 0; mi < 4; ++mi)
#pragma unroll
    for (int ni = 0; ni < 4; ++ni)
#pragma unroll
      for (int r = 0; r < 4; ++r) {
        int gm = rowBase + wm * 64 + mi * 16 + quad * 4 + r;
        int gn = colBase + wn * 64 + ni * 16 + l15;
        C[(size_t)gm * 1024 + gn] = acc[mi][ni][r];
      }
}

// ---------------- K7b: per-column sums of yf (for final BN stats) ----------------
__global__ __launch_bounds__(256) void col_stats(const float* __restrict__ yf,
                                                 double* __restrict__ sum, double* __restrict__ sumsq) {
  int col = blockIdx.x * 256 + threadIdx.x;   // 0..1023
  int r0 = blockIdx.y * 128;
  float s = 0.f, q = 0.f;
  for (int r = 0; r < 128; ++r) {
    float v = yf[(size_t)(r0 + r) * 1024 + col];
    s += v;
    q = fmaf(v, v, q);
  }
  atomicAdd(&sum[col], (double)s);
  atomicAdd(&sumsq[col], (double)q);
}

// ---------------- K8: final normalize + LeakyReLU ----------------
__global__ __launch_bounds__(256) void final_epi(const float* __restrict__ yf,
                                                 const float* __restrict__ cA, const float* __restrict__ cC,
                                                 float* __restrict__ out) {
  int i = blockIdx.x * 256 + threadIdx.x;     // over 8192*1024
  int o = i & 1023;
  float y = fmaf(cA[o], yf[i], cC[o]);
  out[i] = (y > 0.f) ? y : 0.2f * y;
}

extern "C" void kernel_launch(void* const* d_in, const int* in_sizes, int n_in,
                              void* d_out, int out_size, void* d_ws, size_t ws_size,
                              hipStream_t stream) {
  const float* x = (const float*)d_in[0];
  const float* W[4]  = {(const float*)d_in[1], (const float*)d_in[4], (const float*)d_in[7], (const float*)d_in[10]};
  const float* g[4]  = {(const float*)d_in[2], (const float*)d_in[5], (const float*)d_in[8], (const float*)d_in[11]};
  const float* bb[4] = {(const float*)d_in[3], (const float*)d_in[6], (const float*)d_in[9], (const float*)d_in[12]};
  const float* Wf  = (const float*)d_in[13];
  const float* gf  = (const float*)d_in[14];
  const float* bfp = (const float*)d_in[15];
  float* out = (float*)d_out;

  char* ws = (char*)d_ws;
  float*  Df    = (float*)(ws + OFF_DF);
  float*  PT    = (float*)(ws + OFF_PT);
  float*  ymax  = (float*)(ws + OFF_YMAX);
  float*  ymin  = (float*)(ws + OFF_YMIN);
  float*  yf    = (float*)(ws + OFF_YF);
  int*    idxb  = (int*)(ws + OFF_IDX);
  float*  Hbuf  = (float*)(ws + OFF_H);
  unsigned short* fusedb = (unsigned short*)(ws + OFF_FUSB);
  unsigned short* wfb    = (unsigned short*)(ws + OFF_WFB);
  float*  xxb   = (float*)(ws + OFF_XX);
  float*  wcat  = (float*)(ws + OFF_WCAT);
  double* stats = (double*)(ws + OFF_STATS);
  float*  coefb = (float*)(ws + OFF_COEF);

  hipMemsetAsync(stats, 0, 24576, stream);   // zero all stat accumulators (ws is poisoned)
  cvt_bf16<<<(524288 + 255) / 256, 256, 0, stream>>>(Wf, wfb, 524288);

  const int Cin[4]   = {3, 64, 64, 128};
  const int Cout[4]  = {64, 64, 128, 256};
  const int choff[4] = {0, 64, 128, 256};
  const float* Hin = x;
  size_t soff = 0, coff = 0;

  for (int i = 0; i < 4; ++i) {
    int C = Cin[i], oc = Cout[i];
    int l2 = (oc == 64) ? 6 : (oc == 128) ? 7 : 8;
    double* sum = stats + soff;  double* sumsq = sum + oc;  soff += 2 * (size_t)oc;
    float* cA = coefb + coff;    float* cC = cA + oc;       coff += 2 * (size_t)oc;

    xxf_kernel<<<32, 256, 0, stream>>>(Hin, C, xxb);
    distf_kernel<<<dim3(16, 16, 8), 256, 0, stream>>>(Hin, C, xxb, Df);
    if (C == 3)       topk_rerank<3><<<2048, 256, 0, stream>>>(Df, Hin, idxb);
    else if (C == 64) topk_rerank<64><<<2048, 256, 0, stream>>>(Df, Hin, idxb);
    else              topk_rerank<128><<<2048, 256, 0, stream>>>(Df, Hin, idxb);
    wcat_kernel<<<(oc * C + 255) / 256, 256, 0, stream>>>(W[i], wcat, oc, C);
    pt_gemm<<<dim3(2 * oc / 64, 128), 256, 0, stream>>>(Hin, wcat, PT, C, 2 * oc);
    edge_reduce<<<512, 256, 0, stream>>>(PT, idxb, ymax, ymin, sum, sumsq, oc, l2);
    coef_kernel<<<1, 256, 0, stream>>>(sum, sumsq, g[i], bb[i], cA, cC, oc, 163840.0);
    edge_epi<<<(8192 * oc) / 256, 256, 0, stream>>>(ymax, ymin, cA, cC, Hbuf, fusedb, oc, l2, choff[i]);
    Hin = Hbuf;
  }

  double* sumF = stats + soff;  double* sumsqF = sumF + 1024;
  float* cAF = coefb + coff;    float* cCF = cAF + 1024;
  final_gemm_mfma<<<dim3(8, 64), 256, 0, stream>>>(fusedb, wfb, yf);
  col_stats<<<dim3(4, 64), 256, 0, stream>>>(yf, sumF, sumsqF);
  coef_kernel<<<4, 256, 0, stream>>>(sumF, sumsqF, gf, bfp, cAF, cCF, 1024, 8192.0);
  final_epi<<<8192 * 1024 / 256, 256, 0, stream>>>(yf, cAF, cCF, out);
}

// Round 7
// 536.781 us; speedup vs baseline: 2.0093x; 1.1883x over previous
//
#include <hip/hip_runtime.h>
#include <math.h>

#define TILE 64
#define KC 16

typedef __attribute__((ext_vector_type(8))) short short8;
typedef __attribute__((ext_vector_type(4))) float float4v;
typedef const __attribute__((address_space(1))) void* gptr_t;
typedef __attribute__((address_space(3))) void* lptr_t;

// ---------------- workspace layout (bytes) ----------------
#define OFF_DF    0ull          // 8192*1024*4 = 33554432
#define OFF_PT    0ull          // alias: 8192*512*4 = 16777216
#define OFF_YMAX  16777216ull   // alias: 8388608
#define OFF_YMIN  25165824ull   // alias: 8388608
#define OFF_YF    0ull          // alias: 8192*1024*4 = 33554432
#define OFF_IDX   67108864ull   // 655360
#define OFF_H     67764224ull   // 8388608
#define OFF_FUSB  76152832ull   // 8192*512*2 = 8388608 (bf16 fused)
#define OFF_WFB   84541440ull   // 1024*512*2 = 1048576 (bf16 Wf)
#define OFF_XX    85590016ull   // 8192 f32 = 32768
#define OFF_WCAT  85655552ull   // 262144
#define OFF_STATS 85917696ull   // 24576
#define OFF_COEF  85942272ull   // 12288
#define OFF_HHI   85954560ull   // 8192*128*2 = 2097152 (bf16 hi plane, Kp<=128)
#define OFF_HLO   88051712ull   // 2097152 (bf16 lo plane)

__device__ __forceinline__ unsigned short f2bf(float f) {
  unsigned int u = __float_as_uint(f);
  unsigned int r = (u + 0x7fffu + ((u >> 16) & 1u)) >> 16;
  return (unsigned short)r;
}

// ---------------- fp32 tiled GEMM core: C(M,N) = A(M,K) * Bw(N,K)^T ----------------
__device__ __forceinline__ void gemm_tile_loop(
    const float* __restrict__ A, const float* __restrict__ Bw,
    int K, int lda, int ldb, int rowBase, int colBase,
    float acc[4][4], float* As, float* Bs)
{
  const int tid = threadIdx.x;
  const int tx = tid & 15, ty = tid >> 4;
  for (int k0 = 0; k0 < K; k0 += KC) {
    for (int l = 0; l < 4; ++l) {
      int flat = tid * 4 + l;           // 0..1023
      int kk = flat & (KC - 1);
      int row = flat >> 4;
      int gk = k0 + kk;
      float av = 0.f, bv = 0.f;
      if (gk < K) {
        av = A[(size_t)(rowBase + row) * lda + gk];
        bv = Bw[(size_t)(colBase + row) * ldb + gk];
      }
      As[kk * TILE + row] = av;
      Bs[kk * TILE + row] = bv;
    }
    __syncthreads();
#pragma unroll
    for (int kk = 0; kk < KC; ++kk) {
      float a0[4], b0[4];
#pragma unroll
      for (int i = 0; i < 4; ++i) a0[i] = As[kk * TILE + ty * 4 + i];
#pragma unroll
      for (int j = 0; j < 4; ++j) b0[j] = Bs[kk * TILE + tx * 4 + j];
#pragma unroll
      for (int i = 0; i < 4; ++i)
#pragma unroll
        for (int j = 0; j < 4; ++j)
          acc[i][j] = fmaf(a0[i], b0[j], acc[i][j]);
    }
    __syncthreads();
  }
}

// ---------------- K0: squared norms per point (f32, prefilter only) ----------------
__global__ __launch_bounds__(256) void xxf_kernel(const float* __restrict__ H, int C,
                                                  float* __restrict__ xx) {
  int m = blockIdx.x * 256 + threadIdx.x;
  if (m < 8192) {
    float s = 0.f;
    for (int c = 0; c < C; ++c) { float h = H[(size_t)m * C + c]; s = fmaf(h, h, s); }
    xx[m] = s;
  }
}

// ---------------- K0b: split H into bf16 hi + lo planes, zero-padded to Kp ----------------
__global__ __launch_bounds__(256) void split_bf16(const float* __restrict__ H, int C, int l2kp,
                                                  unsigned short* __restrict__ hi,
                                                  unsigned short* __restrict__ lo) {
  int i = blockIdx.x * 256 + threadIdx.x;       // over 8192 << l2kp
  int m = i >> l2kp;
  int c = i & ((1 << l2kp) - 1);
  unsigned short h = 0, l = 0;
  if (c < C) {
    float v = H[(size_t)m * C + c];
    h = f2bf(v);
    float hf = __uint_as_float((unsigned)h << 16);
    l = f2bf(v - hf);
  }
  hi[i] = h;
  lo[i] = l;
}

// ---------------- K1: Gram via split-bf16 MFMA (3 passes) -> neg sq dist (prefilter) ------
__global__ __launch_bounds__(256) void dist_mfma(const unsigned short* __restrict__ Hhi,
                                                 const unsigned short* __restrict__ Hlo,
                                                 const float* __restrict__ xx,
                                                 float* __restrict__ Df, int Kp) {
  __shared__ unsigned short Ash[128 * 32], Asl[128 * 32];
  __shared__ unsigned short Bsh[128 * 32], Bsl[128 * 32];
  const int tid = threadIdx.x;
  const int lane = tid & 63;
  const int w = tid >> 6;
  const int wm = w >> 1, wn = w & 1;
  const int bz = blockIdx.z;
  const int rowBase = bz * 1024 + blockIdx.y * 128;
  const int colBase = bz * 1024 + blockIdx.x * 128;
  const int quad = lane >> 4;
  const int l15 = lane & 15;

  float4v acc[4][4] = {};

  for (int k0 = 0; k0 < Kp; k0 += 32) {
#pragma unroll
    for (int q = 0; q < 2; ++q) {
      int ch = (w * 2 + q) * 64 + lane;          // 0..511 16B-chunks per tile
      int r = ch >> 2, cp = ch & 3;
      size_t offA = (size_t)(rowBase + r) * Kp + k0 + cp * 8;
      size_t offB = (size_t)(colBase + r) * Kp + k0 + cp * 8;
      int seg = (w * 2 + q) * 512;
      __builtin_amdgcn_global_load_lds((gptr_t)(Hhi + offA), (lptr_t)(Ash + seg), 16, 0, 0);
      __builtin_amdgcn_global_load_lds((gptr_t)(Hlo + offA), (lptr_t)(Asl + seg), 16, 0, 0);
      __builtin_amdgcn_global_load_lds((gptr_t)(Hhi + offB), (lptr_t)(Bsh + seg), 16, 0, 0);
      __builtin_amdgcn_global_load_lds((gptr_t)(Hlo + offB), (lptr_t)(Bsl + seg), 16, 0, 0);
    }
    __syncthreads();
    short8 ah[4], al[4], bh[4], bl[4];
#pragma unroll
    for (int mi = 0; mi < 4; ++mi) {
      int ro = (wm * 64 + mi * 16 + l15) * 32 + quad * 8;
      ah[mi] = *(const short8*)(Ash + ro);
      al[mi] = *(const short8*)(Asl + ro);
    }
#pragma unroll
    for (int ni = 0; ni < 4; ++ni) {
      int ro = (wn * 64 + ni * 16 + l15) * 32 + quad * 8;
      bh[ni] = *(const short8*)(Bsh + ro);
      bl[ni] = *(const short8*)(Bsl + ro);
    }
#pragma unroll
    for (int mi = 0; mi < 4; ++mi)
#pragma unroll
      for (int ni = 0; ni < 4; ++ni) {
        acc[mi][ni] = __builtin_amdgcn_mfma_f32_16x16x32_bf16(ah[mi], bh[ni], acc[mi][ni], 0, 0, 0);
        acc[mi][ni] = __builtin_amdgcn_mfma_f32_16x16x32_bf16(ah[mi], bl[ni], acc[mi][ni], 0, 0, 0);
        acc[mi][ni] = __builtin_amdgcn_mfma_f32_16x16x32_bf16(al[mi], bh[ni], acc[mi][ni], 0, 0, 0);
      }
    __syncthreads();
  }
#pragma unroll
  for (int mi = 0; mi < 4; ++mi)
#pragma unroll
    for (int ni = 0; ni < 4; ++ni)
#pragma unroll
      for (int r = 0; r < 4; ++r) {
        int gm = rowBase + wm * 64 + mi * 16 + quad * 4 + r;            // global row
        int gn = blockIdx.x * 128 + wn * 64 + ni * 16 + l15;            // col in batch
        float v = 2.0f * acc[mi][ni][r] - xx[gm] - xx[bz * 1024 + gn];
        Df[(size_t)gm * 1024 + gn] = v;
      }
}

// ---------------- K2: threshold-bisection top-[32..64] superset + exact f64 rank -> top-20 set ----
template<int C>
__global__ __launch_bounds__(256) void topk_rerank(const float* __restrict__ Df,
                                                   const float* __restrict__ H,
                                                   int* __restrict__ idx) {
  __shared__ int    candLds[4][64];
  __shared__ double ndLds[4][64];
  __shared__ int    colLds[4][64];
  const int lane = threadIdx.x & 63;
  const int w = threadIdx.x >> 6;
  const int row = blockIdx.x * 4 + w;              // 0..8191
  const int b = row >> 10;
  const float* drow = Df + (size_t)row * 1024;

  unsigned s[16];
#pragma unroll
  for (int t = 0; t < 16; ++t) {
    unsigned u = __float_as_uint(drow[lane + 64 * t]);
    s[t] = (u & 0x80000000u) ? ~u : (u | 0x80000000u);
  }

  unsigned p = 0;
  for (int bit = 31; bit >= 0; --bit) {
    unsigned cand = p | (1u << bit);
    int c = 0;
#pragma unroll
    for (int t = 0; t < 16; ++t) c += (s[t] > cand) ? 1 : 0;
#pragma unroll
    for (int off = 1; off < 64; off <<= 1) c += __shfl_xor(c, off, 64);
    if (c >= 32) {
      p = cand;
      if (c <= 64) break;
    }
  }

  int k = 0;
#pragma unroll
  for (int t = 0; t < 16; ++t) k += (s[t] > p) ? 1 : 0;
  int incl = k;
#pragma unroll
  for (int off = 1; off < 64; off <<= 1) {
    int v = __shfl_up(incl, off, 64);
    if (lane >= off) incl += v;
  }
  int slot = incl - k;
#pragma unroll
  for (int t = 0; t < 16; ++t) {
    if (s[t] > p) {
      if (slot < 64) candLds[w][slot] = lane + 64 * t;
      ++slot;
    }
  }
  int nsel = __shfl(incl, 63, 64);
  if (nsel > 64) nsel = 64;

  double nd; int col;
  if (lane < nsel) {
    col = candLds[w][lane];
    const float* xi = H + (size_t)row * C;
    const float* xj = H + (size_t)(b * 1024 + col) * C;
    double ssum = 0.0;
    if (C == 3) {
#pragma unroll
      for (int c = 0; c < 3; ++c) {
        double d = (double)xi[c] - (double)xj[c];
        ssum = fma(d, d, ssum);
      }
    } else {
      for (int c = 0; c < C; c += 4) {
        float4v a = *(const float4v*)(xi + c);
        float4v bb = *(const float4v*)(xj + c);
        double d0 = (double)a.x - (double)bb.x;
        double d1 = (double)a.y - (double)bb.y;
        double d2 = (double)a.z - (double)bb.z;
        double d3 = (double)a.w - (double)bb.w;
        ssum = fma(d0, d0, ssum); ssum = fma(d1, d1, ssum);
        ssum = fma(d2, d2, ssum); ssum = fma(d3, d3, ssum);
      }
    }
    nd = -ssum;
  } else {
    nd = -INFINITY; col = 100000 + lane;
  }
  ndLds[w][lane] = nd;
  colLds[w][lane] = col;

  int rank = 0;
#pragma unroll 4
  for (int j = 0; j < 64; ++j) {
    double vj = ndLds[w][j];
    int cj = colLds[w][j];
    rank += (vj > nd || (vj == nd && cj < col)) ? 1 : 0;
  }
  if (rank < 20) idx[(size_t)row * 20 + rank] = col;
}

// ---------------- K3a: Wcat = [W1 ; W2-W1]  (W is (out, 2C) row-major) ----------------
__global__ __launch_bounds__(256) void wcat_kernel(const float* __restrict__ W,
                                                   float* __restrict__ Wcat, int outc, int C) {
  int i = blockIdx.x * 256 + threadIdx.x;
  if (i < outc * C) {
    int o = i / C, c = i % C;
    float w1 = W[(size_t)o * 2 * C + c];
    float w2 = W[(size_t)o * 2 * C + C + c];
    Wcat[(size_t)o * C + c] = w1;
    Wcat[(size_t)(outc + o) * C + c] = w2 - w1;
  }
}

// ---------------- K3b: PT(M, 2*out) = H(M,C) @ Wcat^T ----------------
__global__ __launch_bounds__(256) void pt_gemm(const float* __restrict__ A,
                                               const float* __restrict__ Bw,
                                               float* __restrict__ Out, int K, int Nn) {
  __shared__ float As[KC * TILE], Bs[KC * TILE];
  int rowBase = blockIdx.y * 64, colBase = blockIdx.x * 64;
  float acc[4][4] = {};
  gemm_tile_loop(A, Bw, K, K, K, rowBase, colBase, acc, As, Bs);
  int tx = threadIdx.x & 15, ty = threadIdx.x >> 4;
#pragma unroll
  for (int i = 0; i < 4; ++i)
#pragma unroll
    for (int j = 0; j < 4; ++j)
      Out[(size_t)(rowBase + ty * 4 + i) * Nn + colBase + tx * 4 + j] = acc[i][j];
}

// ---------------- K4: gather + max/min over k + channel stats ----------------
__global__ __launch_bounds__(256) void edge_reduce(const float* __restrict__ PT,
                                                   const int* __restrict__ idx,
                                                   float* __restrict__ ymax, float* __restrict__ ymin,
                                                   double* __restrict__ sum, double* __restrict__ sumsq,
                                                   int outc, int l2) {
  __shared__ int sidx[16 * 20];
  __shared__ float ssum[256], ssq[256];
  int tid = threadIdx.x;
  int base = blockIdx.x * 16;
  for (int i = tid; i < 320; i += 256) sidx[i] = idx[base * 20 + i];
  __syncthreads();
  int o = tid & (outc - 1);
  int rs = tid >> l2;
  int R = 256 >> l2;
  int twoc = 2 * outc;
  float ls = 0.f, lq = 0.f;
  for (int r = rs; r < 16; r += R) {
    int m = base + r;
    int boff = (m >> 10) << 10;
    float tv = PT[(size_t)m * twoc + outc + o];
    float vmax = -INFINITY, vmin = INFINITY;
#pragma unroll
    for (int k = 0; k < 20; ++k) {
      int nb = sidx[r * 20 + k];
      float p = PT[(size_t)(boff + nb) * twoc + o];
      float y = p + tv;
      vmax = fmaxf(vmax, y);
      vmin = fminf(vmin, y);
      ls += y;
      lq = fmaf(y, y, lq);
    }
    ymax[(size_t)m * outc + o] = vmax;
    ymin[(size_t)m * outc + o] = vmin;
  }
  ssum[tid] = ls; ssq[tid] = lq;
  __syncthreads();
  if (tid < outc) {
    float s = ssum[tid], q = ssq[tid];
    for (int rr = 1; rr < R; ++rr) { s += ssum[tid + rr * outc]; q += ssq[tid + rr * outc]; }
    atomicAdd(&sum[tid], (double)s);
    atomicAdd(&sumsq[tid], (double)q);
  }
}

// ---------------- K5: per-channel affine coefficients from stats (f64) ----------------
__global__ __launch_bounds__(256) void coef_kernel(const double* __restrict__ sum,
                                                   const double* __restrict__ sumsq,
                                                   const float* __restrict__ g,
                                                   const float* __restrict__ b,
                                                   float* __restrict__ cA, float* __restrict__ cC,
                                                   int outc, double count) {
  int o = blockIdx.x * 256 + threadIdx.x;
  if (o < outc) {
    double mean = sum[o] / count;
    double var = sumsq[o] / count - mean * mean;
    double a = (double)g[o] / sqrt(var + 1e-5);
    cA[o] = (float)a;
    cC[o] = (float)((double)b[o] - mean * a);
  }
}

// ---------------- K6: pick max/min per sign(a), affine + LeakyReLU, scatter to H & fused(bf16) ----------------
__global__ __launch_bounds__(256) void edge_epi(const float* __restrict__ ymax,
                                                const float* __restrict__ ymin,
                                                const float* __restrict__ cA, const float* __restrict__ cC,
                                                float* __restrict__ Hout, unsigned short* __restrict__ fusedb,
                                                int outc, int l2, int choff) {
  int i = blockIdx.x * 256 + threadIdx.x;    // over 8192*outc
  int m = i >> l2;
  int o = i & (outc - 1);
  float a = cA[o], c = cC[o];
  float v = (a >= 0.f) ? ymax[i] : ymin[i];
  float y = fmaf(a, v, c);
  y = (y > 0.f) ? y : 0.2f * y;
  Hout[i] = y;
  fusedb[(size_t)m * 512 + choff + o] = f2bf(y);
}

// ---------------- K6b: fp32 -> bf16 elementwise ----------------
__global__ __launch_bounds__(256) void cvt_bf16(const float* __restrict__ in,
                                                unsigned short* __restrict__ out, int n) {
  int i = blockIdx.x * 256 + threadIdx.x;
  if (i < n) out[i] = f2bf(in[i]);
}

// ---------------- K7: final GEMM (MFMA bf16): yf(8192,1024) = fusedb @ Wfb^T ----------------
__global__ __launch_bounds__(256) void final_gemm_mfma(const unsigned short* __restrict__ A,
                                                       const unsigned short* __restrict__ B,
                                                       float* __restrict__ C) {
  __shared__ unsigned short As[128 * 32];
  __shared__ unsigned short Bs[128 * 32];
  const int tid = threadIdx.x;
  const int lane = tid & 63;
  const int w = tid >> 6;             // wave 0..3
  const int wm = w >> 1, wn = w & 1;  // 2x2 wave grid, each wave 64x64
  const int rowBase = blockIdx.y * 128;
  const int colBase = blockIdx.x * 128;
  const int quad = lane >> 4;
  const int l15 = lane & 15;

  float4v acc[4][4] = {};

  for (int k0 = 0; k0 < 512; k0 += 32) {
#pragma unroll
    for (int q = 0; q < 2; ++q) {
      int ch = (w * 2 + q) * 64 + lane;          // 0..511, 16B chunks
      int r = ch >> 2, cp = ch & 3;
      const unsigned short* ga = A + (size_t)(rowBase + r) * 512 + k0 + cp * 8;
      const unsigned short* gb = B + (size_t)(colBase + r) * 512 + k0 + cp * 8;
      __builtin_amdgcn_global_load_lds((gptr_t)ga, (lptr_t)(As + (size_t)(w * 2 + q) * 512), 16, 0, 0);
      __builtin_amdgcn_global_load_lds((gptr_t)gb, (lptr_t)(Bs + (size_t)(w * 2 + q) * 512), 16, 0, 0);
    }
    __syncthreads();
    short8 af[4], bf[4];
#pragma unroll
    for (int mi = 0; mi < 4; ++mi)
      af[mi] = *(const short8*)(As + (wm * 64 + mi * 16 + l15) * 32 + quad * 8);
#pragma unroll
    for (int ni = 0; ni < 4; ++ni)
      bf[ni] = *(const short8*)(Bs + (wn * 64 + ni * 16 + l15) * 32 + quad * 8);
#pragma unroll
    for (int mi = 0; mi < 4; ++mi)
#pragma unroll
      for (int ni = 0; ni < 4; ++ni)
        acc[mi][ni] = __builtin_amdgcn_mfma_f32_16x16x32_bf16(af[mi], bf[ni], acc[mi][ni], 0, 0, 0);
    __syncthreads();
  }
#pragma unroll
  for (int mi = 0; mi < 4; ++mi)
#pragma unroll
    for (int ni = 0; ni < 4; ++ni)
#pragma unroll
      for (int r = 0; r < 4; ++r) {
        int gm = rowBase + wm * 64 + mi * 16 + quad * 4 + r;
        int gn = colBase + wn * 64 + ni * 16 + l15;
        C[(size_t)gm * 1024 + gn] = acc[mi][ni][r];
      }
}

// ---------------- K7b: per-column sums of yf (for final BN stats) ----------------
__global__ __launch_bounds__(256) void col_stats(const float* __restrict__ yf,
                                                 double* __restrict__ sum, double* __restrict__ sumsq) {
  int col = blockIdx.x * 256 + threadIdx.x;   // 0..1023
  int r0 = blockIdx.y * 128;
  float s = 0.f, q = 0.f;
  for (int r = 0; r < 128; ++r) {
    float v = yf[(size_t)(r0 + r) * 1024 + col];
    s += v;
    q = fmaf(v, v, q);
  }
  atomicAdd(&sum[col], (double)s);
  atomicAdd(&sumsq[col], (double)q);
}

// ---------------- K8: final normalize + LeakyReLU ----------------
__global__ __launch_bounds__(256) void final_epi(const float* __restrict__ yf,
                                                 const float* __restrict__ cA, const float* __restrict__ cC,
                                                 float* __restrict__ out) {
  int i = blockIdx.x * 256 + threadIdx.x;     // over 8192*1024
  int o = i & 1023;
  float y = fmaf(cA[o], yf[i], cC[o]);
  out[i] = (y > 0.f) ? y : 0.2f * y;
}

extern "C" void kernel_launch(void* const* d_in, const int* in_sizes, int n_in,
                              void* d_out, int out_size, void* d_ws, size_t ws_size,
                              hipStream_t stream) {
  const float* x = (const float*)d_in[0];
  const float* W[4]  = {(const float*)d_in[1], (const float*)d_in[4], (const float*)d_in[7], (const float*)d_in[10]};
  const float* g[4]  = {(const float*)d_in[2], (const float*)d_in[5], (const float*)d_in[8], (const float*)d_in[11]};
  const float* bb[4] = {(const float*)d_in[3], (const float*)d_in[6], (const float*)d_in[9], (const float*)d_in[12]};
  const float* Wf  = (const float*)d_in[13];
  const float* gf  = (const float*)d_in[14];
  const float* bfp = (const float*)d_in[15];
  float* out = (float*)d_out;

  char* ws = (char*)d_ws;
  float*  Df    = (float*)(ws + OFF_DF);
  float*  PT    = (float*)(ws + OFF_PT);
  float*  ymax  = (float*)(ws + OFF_YMAX);
  float*  ymin  = (float*)(ws + OFF_YMIN);
  float*  yf    = (float*)(ws + OFF_YF);
  int*    idxb  = (int*)(ws + OFF_IDX);
  float*  Hbuf  = (float*)(ws + OFF_H);
  unsigned short* fusedb = (unsigned short*)(ws + OFF_FUSB);
  unsigned short* wfb    = (unsigned short*)(ws + OFF_WFB);
  float*  xxb   = (float*)(ws + OFF_XX);
  float*  wcat  = (float*)(ws + OFF_WCAT);
  double* stats = (double*)(ws + OFF_STATS);
  float*  coefb = (float*)(ws + OFF_COEF);
  unsigned short* hhi = (unsigned short*)(ws + OFF_HHI);
  unsigned short* hlo = (unsigned short*)(ws + OFF_HLO);

  hipMemsetAsync(stats, 0, 24576, stream);   // zero all stat accumulators (ws is poisoned)
  cvt_bf16<<<(524288 + 255) / 256, 256, 0, stream>>>(Wf, wfb, 524288);

  const int Cin[4]   = {3, 64, 64, 128};
  const int Cout[4]  = {64, 64, 128, 256};
  const int choff[4] = {0, 64, 128, 256};
  const float* Hin = x;
  size_t soff = 0, coff = 0;

  for (int i = 0; i < 4; ++i) {
    int C = Cin[i], oc = Cout[i];
    int l2 = (oc == 64) ? 6 : (oc == 128) ? 7 : 8;
    int Kp = (C == 3) ? 32 : C;                 // padded K for MFMA (multiple of 32)
    int l2kp = (Kp == 32) ? 5 : (Kp == 64) ? 6 : 7;
    double* sum = stats + soff;  double* sumsq = sum + oc;  soff += 2 * (size_t)oc;
    float* cA = coefb + coff;    float* cC = cA + oc;       coff += 2 * (size_t)oc;

    xxf_kernel<<<32, 256, 0, stream>>>(Hin, C, xxb);
    split_bf16<<<(8192 << l2kp) / 256, 256, 0, stream>>>(Hin, C, l2kp, hhi, hlo);
    dist_mfma<<<dim3(8, 8, 8), 256, 0, stream>>>(hhi, hlo, xxb, Df, Kp);
    if (C == 3)       topk_rerank<3><<<2048, 256, 0, stream>>>(Df, Hin, idxb);
    else if (C == 64) topk_rerank<64><<<2048, 256, 0, stream>>>(Df, Hin, idxb);
    else              topk_rerank<128><<<2048, 256, 0, stream>>>(Df, Hin, idxb);
    wcat_kernel<<<(oc * C + 255) / 256, 256, 0, stream>>>(W[i], wcat, oc, C);
    pt_gemm<<<dim3(2 * oc / 64, 128), 256, 0, stream>>>(Hin, wcat, PT, C, 2 * oc);
    edge_reduce<<<512, 256, 0, stream>>>(PT, idxb, ymax, ymin, sum, sumsq, oc, l2);
    coef_kernel<<<1, 256, 0, stream>>>(sum, sumsq, g[i], bb[i], cA, cC, oc, 163840.0);
    edge_epi<<<(8192 * oc) / 256, 256, 0, stream>>>(ymax, ymin, cA, cC, Hbuf, fusedb, oc, l2, choff[i]);
    Hin = Hbuf;
  }

  double* sumF = stats + soff;  double* sumsqF = sumF + 1024;
  float* cAF = coefb + coff;    float* cCF = cAF + 1024;
  final_gemm_mfma<<<dim3(8, 64), 256, 0, stream>>>(fusedb, wfb, yf);
  col_stats<<<dim3(4, 64), 256, 0, stream>>>(yf, sumF, sumsqF);
  coef_kernel<<<4, 256, 0, stream>>>(sumF, sumsqF, gf, bfp, cAF, cCF, 1024, 8192.0);
  final_epi<<<8192 * 1024 / 256, 256, 0, stream>>>(yf, cAF, cCF, out);
}

// Round 8
// 524.892 us; speedup vs baseline: 2.0548x; 1.0227x over previous
//
#include <hip/hip_runtime.h>
#include <math.h>

#define TILE 64
#define KC 16

typedef __attribute__((ext_vector_type(8))) short short8;
typedef __attribute__((ext_vector_type(4))) float float4v;
typedef const __attribute__((address_space(1))) void* gptr_t;
typedef __attribute__((address_space(3))) void* lptr_t;

// ---------------- workspace layout (bytes) ----------------
#define OFF_DF    0ull          // 8192*1024*4 = 33554432
#define OFF_PT    0ull          // alias: 8192*512*4 = 16777216
#define OFF_YMAX  16777216ull   // alias: 8388608
#define OFF_YMIN  25165824ull   // alias: 8388608
#define OFF_YF    0ull          // alias: 8192*1024*4 = 33554432
#define OFF_IDX   67108864ull   // 655360
#define OFF_H     67764224ull   // 8388608
#define OFF_FUSB  76152832ull   // 8192*512*2 = 8388608 (bf16 fused)
#define OFF_WFB   84541440ull   // 1024*512*2 = 1048576 (bf16 Wf)
#define OFF_XX    85590016ull   // 8192 f32 = 32768
#define OFF_WCAT  85655552ull   // 262144
#define OFF_STATS 85917696ull   // 24576
#define OFF_COEF  85942272ull   // 12288
#define OFF_HHI   85954560ull   // 8192*128*2 = 2097152 (bf16 hi plane, Kp<=128)
#define OFF_HLO   88051712ull   // 2097152 (bf16 lo plane)

__device__ __forceinline__ unsigned short f2bf(float f) {
  unsigned int u = __float_as_uint(f);
  unsigned int r = (u + 0x7fffu + ((u >> 16) & 1u)) >> 16;
  return (unsigned short)r;
}

// ---------------- fp32 tiled GEMM core: C(M,N) = A(M,K) * Bw(N,K)^T ----------------
__device__ __forceinline__ void gemm_tile_loop(
    const float* __restrict__ A, const float* __restrict__ Bw,
    int K, int lda, int ldb, int rowBase, int colBase,
    float acc[4][4], float* As, float* Bs)
{
  const int tid = threadIdx.x;
  const int tx = tid & 15, ty = tid >> 4;
  for (int k0 = 0; k0 < K; k0 += KC) {
    for (int l = 0; l < 4; ++l) {
      int flat = tid * 4 + l;           // 0..1023
      int kk = flat & (KC - 1);
      int row = flat >> 4;
      int gk = k0 + kk;
      float av = 0.f, bv = 0.f;
      if (gk < K) {
        av = A[(size_t)(rowBase + row) * lda + gk];
        bv = Bw[(size_t)(colBase + row) * ldb + gk];
      }
      As[kk * TILE + row] = av;
      Bs[kk * TILE + row] = bv;
    }
    __syncthreads();
#pragma unroll
    for (int kk = 0; kk < KC; ++kk) {
      float a0[4], b0[4];
#pragma unroll
      for (int i = 0; i < 4; ++i) a0[i] = As[kk * TILE + ty * 4 + i];
#pragma unroll
      for (int j = 0; j < 4; ++j) b0[j] = Bs[kk * TILE + tx * 4 + j];
#pragma unroll
      for (int i = 0; i < 4; ++i)
#pragma unroll
        for (int j = 0; j < 4; ++j)
          acc[i][j] = fmaf(a0[i], b0[j], acc[i][j]);
    }
    __syncthreads();
  }
}

// ---------------- K0: squared norms per point (f32, prefilter only) ----------------
__global__ __launch_bounds__(256) void xxf_kernel(const float* __restrict__ H, int C,
                                                  float* __restrict__ xx) {
  int m = blockIdx.x * 256 + threadIdx.x;
  if (m < 8192) {
    float s = 0.f;
    for (int c = 0; c < C; ++c) { float h = H[(size_t)m * C + c]; s = fmaf(h, h, s); }
    xx[m] = s;
  }
}

// ---------------- K0b: split H into bf16 hi + lo planes, zero-padded to Kp ----------------
__global__ __launch_bounds__(256) void split_bf16(const float* __restrict__ H, int C, int l2kp,
                                                  unsigned short* __restrict__ hi,
                                                  unsigned short* __restrict__ lo) {
  int i = blockIdx.x * 256 + threadIdx.x;       // over 8192 << l2kp
  int m = i >> l2kp;
  int c = i & ((1 << l2kp) - 1);
  unsigned short h = 0, l = 0;
  if (c < C) {
    float v = H[(size_t)m * C + c];
    h = f2bf(v);
    float hf = __uint_as_float((unsigned)h << 16);
    l = f2bf(v - hf);
  }
  hi[i] = h;
  lo[i] = l;
}

// ---------------- K1: Gram via split-bf16 MFMA (3 passes) -> neg sq dist (prefilter) ------
__global__ __launch_bounds__(256) void dist_mfma(const unsigned short* __restrict__ Hhi,
                                                 const unsigned short* __restrict__ Hlo,
                                                 const float* __restrict__ xx,
                                                 float* __restrict__ Df, int Kp) {
  __shared__ unsigned short Ash[128 * 32], Asl[128 * 32];
  __shared__ unsigned short Bsh[128 * 32], Bsl[128 * 32];
  const int tid = threadIdx.x;
  const int lane = tid & 63;
  const int w = tid >> 6;
  const int wm = w >> 1, wn = w & 1;
  const int bz = blockIdx.z;
  const int rowBase = bz * 1024 + blockIdx.y * 128;
  const int colBase = bz * 1024 + blockIdx.x * 128;
  const int quad = lane >> 4;
  const int l15 = lane & 15;

  float4v acc[4][4] = {};

  for (int k0 = 0; k0 < Kp; k0 += 32) {
#pragma unroll
    for (int q = 0; q < 2; ++q) {
      int ch = (w * 2 + q) * 64 + lane;          // 0..511 16B-chunks per tile
      int r = ch >> 2, cp = ch & 3;
      size_t offA = (size_t)(rowBase + r) * Kp + k0 + cp * 8;
      size_t offB = (size_t)(colBase + r) * Kp + k0 + cp * 8;
      int seg = (w * 2 + q) * 512;
      __builtin_amdgcn_global_load_lds((gptr_t)(Hhi + offA), (lptr_t)(Ash + seg), 16, 0, 0);
      __builtin_amdgcn_global_load_lds((gptr_t)(Hlo + offA), (lptr_t)(Asl + seg), 16, 0, 0);
      __builtin_amdgcn_global_load_lds((gptr_t)(Hhi + offB), (lptr_t)(Bsh + seg), 16, 0, 0);
      __builtin_amdgcn_global_load_lds((gptr_t)(Hlo + offB), (lptr_t)(Bsl + seg), 16, 0, 0);
    }
    __syncthreads();
    short8 ah[4], al[4], bh[4], bl[4];
#pragma unroll
    for (int mi = 0; mi < 4; ++mi) {
      int ro = (wm * 64 + mi * 16 + l15) * 32 + quad * 8;
      ah[mi] = *(const short8*)(Ash + ro);
      al[mi] = *(const short8*)(Asl + ro);
    }
#pragma unroll
    for (int ni = 0; ni < 4; ++ni) {
      int ro = (wn * 64 + ni * 16 + l15) * 32 + quad * 8;
      bh[ni] = *(const short8*)(Bsh + ro);
      bl[ni] = *(const short8*)(Bsl + ro);
    }
#pragma unroll
    for (int mi = 0; mi < 4; ++mi)
#pragma unroll
      for (int ni = 0; ni < 4; ++ni) {
        acc[mi][ni] = __builtin_amdgcn_mfma_f32_16x16x32_bf16(ah[mi], bh[ni], acc[mi][ni], 0, 0, 0);
        acc[mi][ni] = __builtin_amdgcn_mfma_f32_16x16x32_bf16(ah[mi], bl[ni], acc[mi][ni], 0, 0, 0);
        acc[mi][ni] = __builtin_amdgcn_mfma_f32_16x16x32_bf16(al[mi], bh[ni], acc[mi][ni], 0, 0, 0);
      }
    __syncthreads();
  }
#pragma unroll
  for (int mi = 0; mi < 4; ++mi)
#pragma unroll
    for (int ni = 0; ni < 4; ++ni)
#pragma unroll
      for (int r = 0; r < 4; ++r) {
        int gm = rowBase + wm * 64 + mi * 16 + quad * 4 + r;            // global row
        int gn = blockIdx.x * 128 + wn * 64 + ni * 16 + l15;            // col in batch
        float v = 2.0f * acc[mi][ni][r] - xx[gm] - xx[bz * 1024 + gn];
        Df[(size_t)gm * 1024 + gn] = v;
      }
}

// ---------------- K2: threshold-bisection top-[32..64] superset + exact f64 rank -> top-20 set ----
// One wave per row. All cross-lane reductions via ballot+popcount (no shfl chains).
// col mapping: t=(q*4+r) -> col = 256*q + 4*lane + r  (float4 row loads)
template<int C>
__global__ __launch_bounds__(256) void topk_rerank(const float* __restrict__ Df,
                                                   const float* __restrict__ H,
                                                   int* __restrict__ idx) {
  __shared__ int    candLds[4][64];
  __shared__ double ndLds[4][64];
  __shared__ int    colLds[4][64];
  const int lane = threadIdx.x & 63;
  const int w = threadIdx.x >> 6;
  const int row = blockIdx.x * 4 + w;              // 0..8191
  const int b = row >> 10;
  const float* drow = Df + (size_t)row * 1024;

  unsigned s[16];
#pragma unroll
  for (int q = 0; q < 4; ++q) {
    float4v v = *(const float4v*)(drow + 256 * q + 4 * lane);
#pragma unroll
    for (int r = 0; r < 4; ++r) {
      float f = (r == 0) ? v.x : (r == 1) ? v.y : (r == 2) ? v.z : v.w;
      unsigned u = __float_as_uint(f);
      s[q * 4 + r] = (u & 0x80000000u) ? ~u : (u | 0x80000000u);
    }
  }

  // bisect threshold p: selected = {s > p}, invariant count(p) >= 32, exit when <= 64
  unsigned p = 0;
  for (int bit = 31; bit >= 0; --bit) {
    unsigned cand = p | (1u << bit);
    int c = 0;
#pragma unroll
    for (int t = 0; t < 16; ++t)
      c += __popcll(__ballot(s[t] > cand));
    if (c >= 32) {
      p = cand;
      if (c <= 64) break;
    }
  }

  // compact selected cols to per-wave LDS via ballot prefix (order-agnostic downstream)
  const unsigned long long lt = (1ull << lane) - 1ull;
  int base = 0;
#pragma unroll
  for (int t = 0; t < 16; ++t) {
    unsigned long long m = __ballot(s[t] > p);
    if (s[t] > p) {
      int slot = base + (int)__popcll(m & lt);
      if (slot < 64) candLds[w][slot] = 256 * (t >> 2) + 4 * lane + (t & 3);
    }
    base += (int)__popcll(m);
  }
  int nsel = base > 64 ? 64 : base;

  // exact f64 re-rank (direct form, no cancellation), one candidate per lane
  double nd; int col;
  if (lane < nsel) {
    col = candLds[w][lane];
    const float* xi = H + (size_t)row * C;
    const float* xj = H + (size_t)(b * 1024 + col) * C;
    double ssum = 0.0;
    if (C == 3) {
#pragma unroll
      for (int c = 0; c < 3; ++c) {
        double d = (double)xi[c] - (double)xj[c];
        ssum = fma(d, d, ssum);
      }
    } else {
      for (int c = 0; c < C; c += 4) {
        float4v a = *(const float4v*)(xi + c);
        float4v bb = *(const float4v*)(xj + c);
        double d0 = (double)a.x - (double)bb.x;
        double d1 = (double)a.y - (double)bb.y;
        double d2 = (double)a.z - (double)bb.z;
        double d3 = (double)a.w - (double)bb.w;
        ssum = fma(d0, d0, ssum); ssum = fma(d1, d1, ssum);
        ssum = fma(d2, d2, ssum); ssum = fma(d3, d3, ssum);
      }
    }
    nd = -ssum;
  } else {
    nd = -INFINITY; col = 100000 + lane;
  }
  ndLds[w][lane] = nd;
  colLds[w][lane] = col;

  // rank by counting beats (value desc, col asc) -- LDS broadcast reads
  int rank = 0;
#pragma unroll 4
  for (int j = 0; j < 64; ++j) {
    double vj = ndLds[w][j];
    int cj = colLds[w][j];
    rank += (vj > nd || (vj == nd && cj < col)) ? 1 : 0;
  }
  if (rank < 20) idx[(size_t)row * 20 + rank] = col;
}

// ---------------- K3a: Wcat = [W1 ; W2-W1]  (W is (out, 2C) row-major) ----------------
__global__ __launch_bounds__(256) void wcat_kernel(const float* __restrict__ W,
                                                   float* __restrict__ Wcat, int outc, int C) {
  int i = blockIdx.x * 256 + threadIdx.x;
  if (i < outc * C) {
    int o = i / C, c = i % C;
    float w1 = W[(size_t)o * 2 * C + c];
    float w2 = W[(size_t)o * 2 * C + C + c];
    Wcat[(size_t)o * C + c] = w1;
    Wcat[(size_t)(outc + o) * C + c] = w2 - w1;
  }
}

// ---------------- K3b: PT(M, 2*out) = H(M,C) @ Wcat^T ----------------
__global__ __launch_bounds__(256) void pt_gemm(const float* __restrict__ A,
                                               const float* __restrict__ Bw,
                                               float* __restrict__ Out, int K, int Nn) {
  __shared__ float As[KC * TILE], Bs[KC * TILE];
  int rowBase = blockIdx.y * 64, colBase = blockIdx.x * 64;
  float acc[4][4] = {};
  gemm_tile_loop(A, Bw, K, K, K, rowBase, colBase, acc, As, Bs);
  int tx = threadIdx.x & 15, ty = threadIdx.x >> 4;
#pragma unroll
  for (int i = 0; i < 4; ++i)
#pragma unroll
    for (int j = 0; j < 4; ++j)
      Out[(size_t)(rowBase + ty * 4 + i) * Nn + colBase + tx * 4 + j] = acc[i][j];
}

// ---------------- K4: gather + max/min over k + channel stats ----------------
__global__ __launch_bounds__(256) void edge_reduce(const float* __restrict__ PT,
                                                   const int* __restrict__ idx,
                                                   float* __restrict__ ymax, float* __restrict__ ymin,
                                                   double* __restrict__ sum, double* __restrict__ sumsq,
                                                   int outc, int l2) {
  __shared__ int sidx[16 * 20];
  __shared__ float ssum[256], ssq[256];
  int tid = threadIdx.x;
  int base = blockIdx.x * 16;
  for (int i = tid; i < 320; i += 256) sidx[i] = idx[base * 20 + i];
  __syncthreads();
  int o = tid & (outc - 1);
  int rs = tid >> l2;
  int R = 256 >> l2;
  int twoc = 2 * outc;
  float ls = 0.f, lq = 0.f;
  for (int r = rs; r < 16; r += R) {
    int m = base + r;
    int boff = (m >> 10) << 10;
    float tv = PT[(size_t)m * twoc + outc + o];
    float vmax = -INFINITY, vmin = INFINITY;
#pragma unroll
    for (int k = 0; k < 20; ++k) {
      int nb = sidx[r * 20 + k];
      float p = PT[(size_t)(boff + nb) * twoc + o];
      float y = p + tv;
      vmax = fmaxf(vmax, y);
      vmin = fminf(vmin, y);
      ls += y;
      lq = fmaf(y, y, lq);
    }
    ymax[(size_t)m * outc + o] = vmax;
    ymin[(size_t)m * outc + o] = vmin;
  }
  ssum[tid] = ls; ssq[tid] = lq;
  __syncthreads();
  if (tid < outc) {
    float s = ssum[tid], q = ssq[tid];
    for (int rr = 1; rr < R; ++rr) { s += ssum[tid + rr * outc]; q += ssq[tid + rr * outc]; }
    atomicAdd(&sum[tid], (double)s);
    atomicAdd(&sumsq[tid], (double)q);
  }
}

// ---------------- K5: per-channel affine coefficients from stats (f64) ----------------
__global__ __launch_bounds__(256) void coef_kernel(const double* __restrict__ sum,
                                                   const double* __restrict__ sumsq,
                                                   const float* __restrict__ g,
                                                   const float* __restrict__ b,
                                                   float* __restrict__ cA, float* __restrict__ cC,
                                                   int outc, double count) {
  int o = blockIdx.x * 256 + threadIdx.x;
  if (o < outc) {
    double mean = sum[o] / count;
    double var = sumsq[o] / count - mean * mean;
    double a = (double)g[o] / sqrt(var + 1e-5);
    cA[o] = (float)a;
    cC[o] = (float)((double)b[o] - mean * a);
  }
}

// ---------------- K6: pick max/min per sign(a), affine + LeakyReLU, scatter to H & fused(bf16) ----------------
__global__ __launch_bounds__(256) void edge_epi(const float* __restrict__ ymax,
                                                const float* __restrict__ ymin,
                                                const float* __restrict__ cA, const float* __restrict__ cC,
                                                float* __restrict__ Hout, unsigned short* __restrict__ fusedb,
                                                int outc, int l2, int choff) {
  int i = blockIdx.x * 256 + threadIdx.x;    // over 8192*outc
  int m = i >> l2;
  int o = i & (outc - 1);
  float a = cA[o], c = cC[o];
  float v = (a >= 0.f) ? ymax[i] : ymin[i];
  float y = fmaf(a, v, c);
  y = (y > 0.f) ? y : 0.2f * y;
  Hout[i] = y;
  fusedb[(size_t)m * 512 + choff + o] = f2bf(y);
}

// ---------------- K6b: fp32 -> bf16 elementwise ----------------
__global__ __launch_bounds__(256) void cvt_bf16(const float* __restrict__ in,
                                                unsigned short* __restrict__ out, int n) {
  int i = blockIdx.x * 256 + threadIdx.x;
  if (i < n) out[i] = f2bf(in[i]);
}

// ---------------- K7: final GEMM (MFMA bf16): yf(8192,1024) = fusedb @ Wfb^T ----------------
__global__ __launch_bounds__(256) void final_gemm_mfma(const unsigned short* __restrict__ A,
                                                       const unsigned short* __restrict__ B,
                                                       float* __restrict__ C) {
  __shared__ unsigned short As[128 * 32];
  __shared__ unsigned short Bs[128 * 32];
  const int tid = threadIdx.x;
  const int lane = tid & 63;
  const int w = tid >> 6;             // wave 0..3
  const int wm = w >> 1, wn = w & 1;  // 2x2 wave grid, each wave 64x64
  const int rowBase = blockIdx.y * 128;
  const int colBase = blockIdx.x * 128;
  const int quad = lane >> 4;
  const int l15 = lane & 15;

  float4v acc[4][4] = {};

  for (int k0 = 0; k0 < 512; k0 += 32) {
#pragma unroll
    for (int q = 0; q < 2; ++q) {
      int ch = (w * 2 + q) * 64 + lane;          // 0..511, 16B chunks
      int r = ch >> 2, cp = ch & 3;
      const unsigned short* ga = A + (size_t)(rowBase + r) * 512 + k0 + cp * 8;
      const unsigned short* gb = B + (size_t)(colBase + r) * 512 + k0 + cp * 8;
      __builtin_amdgcn_global_load_lds((gptr_t)ga, (lptr_t)(As + (size_t)(w * 2 + q) * 512), 16, 0, 0);
      __builtin_amdgcn_global_load_lds((gptr_t)gb, (lptr_t)(Bs + (size_t)(w * 2 + q) * 512), 16, 0, 0);
    }
    __syncthreads();
    short8 af[4], bf[4];
#pragma unroll
    for (int mi = 0; mi < 4; ++mi)
      af[mi] = *(const short8*)(As + (wm * 64 + mi * 16 + l15) * 32 + quad * 8);
#pragma unroll
    for (int ni = 0; ni < 4; ++ni)
      bf[ni] = *(const short8*)(Bs + (wn * 64 + ni * 16 + l15) * 32 + quad * 8);
#pragma unroll
    for (int mi = 0; mi < 4; ++mi)
#pragma unroll
      for (int ni = 0; ni < 4; ++ni)
        acc[mi][ni] = __builtin_amdgcn_mfma_f32_16x16x32_bf16(af[mi], bf[ni], acc[mi][ni], 0, 0, 0);
    __syncthreads();
  }
#pragma unroll
  for (int mi = 0; mi < 4; ++mi)
#pragma unroll
    for (int ni = 0; ni < 4; ++ni)
#pragma unroll
      for (int r = 0; r < 4; ++r) {
        int gm = rowBase + wm * 64 + mi * 16 + quad * 4 + r;
        int gn = colBase + wn * 64 + ni * 16 + l15;
        C[(size_t)gm * 1024 + gn] = acc[mi][ni][r];
      }
}

// ---------------- K7b: per-column sums of yf (for final BN stats) ----------------
__global__ __launch_bounds__(256) void col_stats(const float* __restrict__ yf,
                                                 double* __restrict__ sum, double* __restrict__ sumsq) {
  int col = blockIdx.x * 256 + threadIdx.x;   // 0..1023
  int r0 = blockIdx.y * 128;
  float s = 0.f, q = 0.f;
  for (int r = 0; r < 128; ++r) {
    float v = yf[(size_t)(r0 + r) * 1024 + col];
    s += v;
    q = fmaf(v, v, q);
  }
  atomicAdd(&sum[col], (double)s);
  atomicAdd(&sumsq[col], (double)q);
}

// ---------------- K8: final normalize + LeakyReLU ----------------
__global__ __launch_bounds__(256) void final_epi(const float* __restrict__ yf,
                                                 const float* __restrict__ cA, const float* __restrict__ cC,
                                                 float* __restrict__ out) {
  int i = blockIdx.x * 256 + threadIdx.x;     // over 8192*1024
  int o = i & 1023;
  float y = fmaf(cA[o], yf[i], cC[o]);
  out[i] = (y > 0.f) ? y : 0.2f * y;
}

extern "C" void kernel_launch(void* const* d_in, const int* in_sizes, int n_in,
                              void* d_out, int out_size, void* d_ws, size_t ws_size,
                              hipStream_t stream) {
  const float* x = (const float*)d_in[0];
  const float* W[4]  = {(const float*)d_in[1], (const float*)d_in[4], (const float*)d_in[7], (const float*)d_in[10]};
  const float* g[4]  = {(const float*)d_in[2], (const float*)d_in[5], (const float*)d_in[8], (const float*)d_in[11]};
  const float* bb[4] = {(const float*)d_in[3], (const float*)d_in[6], (const float*)d_in[9], (const float*)d_in[12]};
  const float* Wf  = (const float*)d_in[13];
  const float* gf  = (const float*)d_in[14];
  const float* bfp = (const float*)d_in[15];
  float* out = (float*)d_out;

  char* ws = (char*)d_ws;
  float*  Df    = (float*)(ws + OFF_DF);
  float*  PT    = (float*)(ws + OFF_PT);
  float*  ymax  = (float*)(ws + OFF_YMAX);
  float*  ymin  = (float*)(ws + OFF_YMIN);
  float*  yf    = (float*)(ws + OFF_YF);
  int*    idxb  = (int*)(ws + OFF_IDX);
  float*  Hbuf  = (float*)(ws + OFF_H);
  unsigned short* fusedb = (unsigned short*)(ws + OFF_FUSB);
  unsigned short* wfb    = (unsigned short*)(ws + OFF_WFB);
  float*  xxb   = (float*)(ws + OFF_XX);
  float*  wcat  = (float*)(ws + OFF_WCAT);
  double* stats = (double*)(ws + OFF_STATS);
  float*  coefb = (float*)(ws + OFF_COEF);
  unsigned short* hhi = (unsigned short*)(ws + OFF_HHI);
  unsigned short* hlo = (unsigned short*)(ws + OFF_HLO);

  hipMemsetAsync(stats, 0, 24576, stream);   // zero all stat accumulators (ws is poisoned)
  cvt_bf16<<<(524288 + 255) / 256, 256, 0, stream>>>(Wf, wfb, 524288);

  const int Cin[4]   = {3, 64, 64, 128};
  const int Cout[4]  = {64, 64, 128, 256};
  const int choff[4] = {0, 64, 128, 256};
  const float* Hin = x;
  size_t soff = 0, coff = 0;

  for (int i = 0; i < 4; ++i) {
    int C = Cin[i], oc = Cout[i];
    int l2 = (oc == 64) ? 6 : (oc == 128) ? 7 : 8;
    int Kp = (C == 3) ? 32 : C;                 // padded K for MFMA (multiple of 32)
    int l2kp = (Kp == 32) ? 5 : (Kp == 64) ? 6 : 7;
    double* sum = stats + soff;  double* sumsq = sum + oc;  soff += 2 * (size_t)oc;
    float* cA = coefb + coff;    float* cC = cA + oc;       coff += 2 * (size_t)oc;

    xxf_kernel<<<32, 256, 0, stream>>>(Hin, C, xxb);
    split_bf16<<<(8192 << l2kp) / 256, 256, 0, stream>>>(Hin, C, l2kp, hhi, hlo);
    dist_mfma<<<dim3(8, 8, 8), 256, 0, stream>>>(hhi, hlo, xxb, Df, Kp);
    if (C == 3)       topk_rerank<3><<<2048, 256, 0, stream>>>(Df, Hin, idxb);
    else if (C == 64) topk_rerank<64><<<2048, 256, 0, stream>>>(Df, Hin, idxb);
    else              topk_rerank<128><<<2048, 256, 0, stream>>>(Df, Hin, idxb);
    wcat_kernel<<<(oc * C + 255) / 256, 256, 0, stream>>>(W[i], wcat, oc, C);
    pt_gemm<<<dim3(2 * oc / 64, 128), 256, 0, stream>>>(Hin, wcat, PT, C, 2 * oc);
    edge_reduce<<<512, 256, 0, stream>>>(PT, idxb, ymax, ymin, sum, sumsq, oc, l2);
    coef_kernel<<<1, 256, 0, stream>>>(sum, sumsq, g[i], bb[i], cA, cC, oc, 163840.0);
    edge_epi<<<(8192 * oc) / 256, 256, 0, stream>>>(ymax, ymin, cA, cC, Hbuf, fusedb, oc, l2, choff[i]);
    Hin = Hbuf;
  }

  double* sumF = stats + soff;  double* sumsqF = sumF + 1024;
  float* cAF = coefb + coff;    float* cCF = cAF + 1024;
  final_gemm_mfma<<<dim3(8, 64), 256, 0, stream>>>(fusedb, wfb, yf);
  col_stats<<<dim3(4, 64), 256, 0, stream>>>(yf, sumF, sumsqF);
  coef_kernel<<<4, 256, 0, stream>>>(sumF, sumsqF, gf, bfp, cAF, cCF, 1024, 8192.0);
  final_epi<<<8192 * 1024 / 256, 256, 0, stream>>>(yf, cAF, cCF, out);
}